// Round 3
// baseline (688.055 us; speedup 1.0000x reference)
//
#include <hip/hip_runtime.h>
#include <hip/hip_bf16.h>

// ---------------------------------------------------------------------------
// GNN action-value net, MI355X. Round 3: all float tensors are FP32
// (per reference dtype; rounds 1-2 NaN'd by misreading f32 buffers as bf16).
//  * ONE kernel, one block per graph (1024 blocks x 256 threads).
//  * No d_ws usage. All LDS zero-initialized. int32 index arrays.
//  * Weights read directly from global as f32 (L2-hot, ~260KB shared by all
//    blocks); big matmuls use float4 loads.
// LDS ~94KB -> 1 block/CU this round; optimize occupancy once green.
// ---------------------------------------------------------------------------

#define NPG 64
#define DEG 16
#define EPG (NPG*DEG)          // 1024 edges / graph
#define NEPG 256
#define B_GR 1024
#define N_NODES (B_GR*NPG)
#define E_TOT (N_NODES*DEG)    // 1048576
#define EMB 64
#define HID 128
#define NOUT 101
#define OUT_PG (1 + NPG*NOUT + NEPG)   // 6721
#define SROW 132               // padded LDS row stride (floats)

// A: LDS f32 [64 x K] stride SROW. Bw: global f32 [K x HID] row-major.
// C: LDS f32 [64 x HID] stride SROW. 16x16 threads, 4r x 8c per thread.
template<int K, bool RELU, bool BIAS>
__device__ __forceinline__ void mm_f32(const float* __restrict__ A,
                                       const float* __restrict__ Bw,
                                       const float* __restrict__ bias,
                                       float* __restrict__ C, int tid)
{
  const int r0 = (tid >> 4) * 4;
  const int c0 = (tid & 15) * 8;
  float acc[4][8] = {};
  #pragma unroll 4
  for (int k = 0; k < K; ++k) {
    const float4 b0 = *(const float4*)(Bw + k*HID + c0);
    const float4 b1 = *(const float4*)(Bw + k*HID + c0 + 4);
    const float bv[8] = {b0.x,b0.y,b0.z,b0.w,b1.x,b1.y,b1.z,b1.w};
    float av[4];
    #pragma unroll
    for (int i = 0; i < 4; ++i) av[i] = A[(r0+i)*SROW + k];
    #pragma unroll
    for (int i = 0; i < 4; ++i)
      #pragma unroll
      for (int j = 0; j < 8; ++j) acc[i][j] = fmaf(av[i], bv[j], acc[i][j]);
  }
  #pragma unroll
  for (int i = 0; i < 4; ++i) {
    #pragma unroll
    for (int j = 0; j < 8; ++j) {
      float v = acc[i][j];
      if (BIAS) v += bias[c0+j];
      if (RELU) v = fmaxf(v, 0.f);
      C[(r0+i)*SROW + c0 + j] = v;
    }
  }
}

__global__ __launch_bounds__(256) void graph_kernel(
    const float* __restrict__ node_tab, const float* __restrict__ edge_tab,
    const float* __restrict__ c1_w,  const float* __restrict__ c1_we,
    const float* __restrict__ c1_as, const float* __restrict__ c1_ad,
    const float* __restrict__ c1_ae, const float* __restrict__ c1_b,
    const float* __restrict__ c2_w,  const float* __restrict__ c2_we,
    const float* __restrict__ c2_as, const float* __restrict__ c2_ad,
    const float* __restrict__ c2_ae, const float* __restrict__ c2_b,
    const float* __restrict__ s_w1,  const float* __restrict__ s_b1,
    const float* __restrict__ s_w2,  const float* __restrict__ s_b2,
    const float* __restrict__ n_w1,  const float* __restrict__ n_b1,
    const float* __restrict__ n_w2,  const float* __restrict__ n_b2,
    const float* __restrict__ e_w1,  const float* __restrict__ e_b1,
    const float* __restrict__ e_w2,  const float* __restrict__ e_b2,
    const int* __restrict__ x,  const int* __restrict__ ei,
    const int* __restrict__ ea, const int* __restrict__ nedg,
    float* __restrict__ out)
{
  const int gid = blockIdx.x;
  const int tid = threadIdx.x;
  const int nb = gid * NPG;
  const int ebase = gid * EPG;

  __shared__ __align__(16) float bufA[NPG*SROW];   // 33792B
  __shared__ __align__(16) float bufB[NPG*SROW];   // 33792B
  __shared__ float lg[EPG];                        // logits
  __shared__ float alpha[EPG];                     // softmax weights
  __shared__ int csr[EPG], lsrc[EPG], ldst[EPG], eat[EPG];
  __shared__ int xs[NPG], cnt[NPG], cofs[NPG+1], cpos[NPG];
  __shared__ float ns[NPG], nd[NPG], wk[NPG];
  __shared__ float gp[HID], zh[HID], eb1s[HID], ew2s[HID];
  __shared__ float hcl[4];

  // ---- defensive zero-init of ALL LDS ----
  for (int i = tid; i < NPG*SROW; i += 256) { bufA[i] = 0.f; bufB[i] = 0.f; }
  for (int i = tid; i < EPG; i += 256) {
    lg[i] = 0.f; alpha[i] = 0.f; csr[i] = 0; lsrc[i] = 0; ldst[i] = 0; eat[i] = 0;
  }
  if (tid < NPG) { xs[tid]=0; cnt[tid]=0; cpos[tid]=0; ns[tid]=0.f; nd[tid]=0.f; wk[tid]=0.f; }
  if (tid < HID) { gp[tid]=0.f; zh[tid]=0.f; eb1s[tid]=0.f; ew2s[tid]=0.f; }
  if (tid < NPG+1) cofs[tid] = 0;
  if (tid < 4) hcl[tid] = 0.f;
  __syncthreads();

  // ---- topology ----
  for (int k = tid; k < EPG; k += 256) {
    lsrc[k] = ei[ebase + k] - nb;
    ldst[k] = ei[E_TOT + ebase + k] - nb;
    eat[k]  = ea[ebase + k];
  }
  if (tid < NPG) xs[tid] = x[nb + tid];
  __syncthreads();

  // ---- stage embeddings into bufB[:, 0:64] ----
  for (int i = tid; i < NPG*EMB; i += 256) {
    const int n = i >> 6, k = i & (EMB-1);
    bufB[n*SROW + k] = node_tab[xs[n]*EMB + k];
  }
  __syncthreads();

  // ---- h1pre = emb @ c1_w  (K=64) -> bufA ----
  mm_f32<EMB, false, false>(bufB, c1_w, nullptr, bufA, tid);
  __syncthreads();

  // ---- layer-1 attention scalars ----
  if (tid < NPG) {
    float a = 0.f, d = 0.f;
    const float* hp = bufA + tid*SROW;
    for (int c = 0; c < HID; ++c) { const float v = hp[c]; a = fmaf(v, c1_as[c], a); d = fmaf(v, c1_ad[c], d); }
    ns[tid] = a; nd[tid] = d;
  }
  if (tid >= 64 && tid < 128) {   // wk[k] = sum_j c1_we[k][j]*c1_ae[j]
    const int k = tid - 64;
    float a = 0.f;
    for (int j = 0; j < HID; ++j) a = fmaf(c1_we[k*HID + j], c1_ae[j], a);
    wk[k] = a;
  }
  __syncthreads();
  if (tid < 4) {                  // hcl[t] = edge_tab[t] . wk
    float a = 0.f;
    for (int k = 0; k < EMB; ++k) a = fmaf(edge_tab[tid*EMB + k], wk[k], a);
    hcl[tid] = a;
  }
  __syncthreads();

  // ---- layer-1 logits + degree count ----
  for (int k = tid; k < EPG; k += 256) {
    const float l = ns[lsrc[k]] + nd[ldst[k]] + hcl[eat[k]];
    lg[k] = (l > 0.f) ? l : 0.2f * l;
    atomicAdd(&cnt[ldst[k]], 1);
  }
  __syncthreads();
  if (tid == 0) {
    int s = 0;
    for (int i = 0; i < NPG; ++i) { cofs[i] = s; cpos[i] = s; s += cnt[i]; }
    cofs[NPG] = s;
  }
  __syncthreads();
  for (int k = tid; k < EPG; k += 256) {
    const int p = atomicAdd(&cpos[ldst[k]], 1);
    csr[p] = k;
  }
  __syncthreads();

  // ---- layer-1 segment softmax -> alpha ----
  if (tid < NPG) {
    const int s = cofs[tid], e = cofs[tid+1];
    float m = -1e30f;
    for (int i = s; i < e; ++i) m = fmaxf(m, lg[csr[i]]);
    float den = 0.f;
    for (int i = s; i < e; ++i) { const float ex = __expf(lg[csr[i]] - m); alpha[csr[i]] = ex; den += ex; }
    const float inv = 1.f / (den + 1e-16f);
    for (int i = s; i < e; ++i) alpha[csr[i]] *= inv;
  }
  __syncthreads();

  // ---- layer-1 scatter: h1 = relu(sum alpha*h1pre[src] + c1_b) -> bufB ----
  {
    const int n  = tid >> 2;
    const int cb = (tid & 3) * 32;
    float4 acc[8] = {};
    const int s = cofs[n], e = cofs[n+1];
    for (int i = s; i < e; ++i) {
      const int k = csr[i];
      const float a = alpha[k];
      const float4* hp = (const float4*)(bufA + lsrc[k]*SROW + cb);
      #pragma unroll
      for (int q = 0; q < 8; ++q) {
        const float4 h = hp[q];
        acc[q].x = fmaf(a, h.x, acc[q].x); acc[q].y = fmaf(a, h.y, acc[q].y);
        acc[q].z = fmaf(a, h.z, acc[q].z); acc[q].w = fmaf(a, h.w, acc[q].w);
      }
    }
    #pragma unroll
    for (int q = 0; q < 8; ++q) {
      float4 v = acc[q];
      v.x = fmaxf(v.x + c1_b[cb+q*4+0], 0.f);
      v.y = fmaxf(v.y + c1_b[cb+q*4+1], 0.f);
      v.z = fmaxf(v.z + c1_b[cb+q*4+2], 0.f);
      v.w = fmaxf(v.w + c1_b[cb+q*4+3], 0.f);
      *(float4*)(bufB + n*SROW + cb + q*4) = v;
    }
  }
  __syncthreads();

  // ---- h2pre = h1 @ c2_w (K=128) -> bufA ----
  mm_f32<HID, false, false>(bufB, c2_w, nullptr, bufA, tid);
  __syncthreads();

  // ---- layer-2 attention scalars ----
  if (tid < NPG) {
    float a = 0.f, d = 0.f;
    const float* hp = bufA + tid*SROW;
    for (int c = 0; c < HID; ++c) { const float v = hp[c]; a = fmaf(v, c2_as[c], a); d = fmaf(v, c2_ad[c], d); }
    ns[tid] = a; nd[tid] = d;
  }
  if (tid >= 64 && tid < 128) {
    const int k = tid - 64;
    float a = 0.f;
    for (int j = 0; j < HID; ++j) a = fmaf(c2_we[k*HID + j], c2_ae[j], a);
    wk[k] = a;
  }
  __syncthreads();
  if (tid < 4) {
    float a = 0.f;
    for (int k = 0; k < EMB; ++k) a = fmaf(edge_tab[tid*EMB + k], wk[k], a);
    hcl[tid] = a;
  }
  __syncthreads();

  // ---- layer-2 logits / softmax / scatter (reuse csr) ----
  for (int k = tid; k < EPG; k += 256) {
    const float l = ns[lsrc[k]] + nd[ldst[k]] + hcl[eat[k]];
    lg[k] = (l > 0.f) ? l : 0.2f * l;
  }
  __syncthreads();
  if (tid < NPG) {
    const int s = cofs[tid], e = cofs[tid+1];
    float m = -1e30f;
    for (int i = s; i < e; ++i) m = fmaxf(m, lg[csr[i]]);
    float den = 0.f;
    for (int i = s; i < e; ++i) { const float ex = __expf(lg[csr[i]] - m); alpha[csr[i]] = ex; den += ex; }
    const float inv = 1.f / (den + 1e-16f);
    for (int i = s; i < e; ++i) alpha[csr[i]] *= inv;
  }
  __syncthreads();
  {
    const int n  = tid >> 2;
    const int cb = (tid & 3) * 32;
    float4 acc[8] = {};
    const int s = cofs[n], e = cofs[n+1];
    for (int i = s; i < e; ++i) {
      const int k = csr[i];
      const float a = alpha[k];
      const float4* hp = (const float4*)(bufA + lsrc[k]*SROW + cb);
      #pragma unroll
      for (int q = 0; q < 8; ++q) {
        const float4 h = hp[q];
        acc[q].x = fmaf(a, h.x, acc[q].x); acc[q].y = fmaf(a, h.y, acc[q].y);
        acc[q].z = fmaf(a, h.z, acc[q].z); acc[q].w = fmaf(a, h.w, acc[q].w);
      }
    }
    #pragma unroll
    for (int q = 0; q < 8; ++q) {
      float4 v = acc[q];
      v.x += c2_b[cb+q*4+0]; v.y += c2_b[cb+q*4+1];
      v.z += c2_b[cb+q*4+2]; v.w += c2_b[cb+q*4+3];
      *(float4*)(bufB + n*SROW + cb + q*4) = v;     // h2 -> bufB
    }
  }
  __syncthreads();

  // ---- graph pooling + stop head ----
  if (tid < HID) {
    float s = 0.f;
    for (int n2 = 0; n2 < NPG; ++n2) s += bufB[n2*SROW + tid];
    gp[tid] = s;
  }
  __syncthreads();
  if (tid < HID) {
    float a = s_b1[tid];
    for (int c = 0; c < HID; ++c) a = fmaf(gp[c], s_w1[c*HID + tid], a);
    zh[tid] = fmaxf(a, 0.f);
  }
  __syncthreads();
  if (tid == 0) {
    float s = s_b2[0];
    for (int j = 0; j < HID; ++j) s = fmaf(zh[j], s_w2[j], s);
    out[(size_t)gid*OUT_PG] = s;
  }
  __syncthreads();

  // ---- addnode head ----
  mm_f32<HID, true, true>(bufB, n_w1, n_b1, bufA, tid);   // a1 -> bufA
  __syncthreads();
  if (tid < 208) {  // 16 row-tiles x 13 col-tiles of 4x8 covering 64x104
    const int rt = tid / 13, ct = tid - rt*13;
    const int r0 = rt*4, c0 = ct*8;
    float acc[4][8] = {};
    for (int k = 0; k < HID; ++k) {
      float bv[8];
      #pragma unroll
      for (int j = 0; j < 8; ++j) {
        const int o = c0 + j;
        bv[j] = (o < NOUT) ? n_w2[k*NOUT + o] : 0.f;
      }
      float av[4];
      #pragma unroll
      for (int i = 0; i < 4; ++i) av[i] = bufA[(r0+i)*SROW + k];
      #pragma unroll
      for (int i = 0; i < 4; ++i)
        #pragma unroll
        for (int j = 0; j < 8; ++j) acc[i][j] = fmaf(av[i], bv[j], acc[i][j]);
    }
    const size_t ob = (size_t)gid*OUT_PG + 1;
    #pragma unroll
    for (int i = 0; i < 4; ++i) {
      #pragma unroll
      for (int j = 0; j < 8; ++j) {
        const int o = c0 + j;
        if (o < NOUT)
          out[ob + (size_t)(r0+i)*NOUT + o] = acc[i][j] + n_b2[o];
      }
    }
  }
  __syncthreads();

  // ---- addedge head ----
  mm_f32<HID, false, false>(bufB, e_w1, nullptr, bufA, tid);  // u -> bufA
  if (tid < HID) { eb1s[tid] = e_b1[tid]; ew2s[tid] = e_w2[tid]; }
  __syncthreads();
  {
    const int r = gid*NEPG + tid;
    const int i = nedg[2*r]     - nb;
    const int j = nedg[2*r + 1] - nb;
    const float* ui = bufA + i*SROW;
    const float* uj = bufA + j*SROW;
    float s = 0.f;
    for (int c = 0; c < HID; ++c) {
      float v = ui[c] + uj[c] + eb1s[c];
      v = fmaxf(v, 0.f);
      s = fmaf(v, ew2s[c], s);
    }
    out[(size_t)gid*OUT_PG + 1 + NPG*NOUT + tid] = s + e_b2[0];
  }
}

// ---------------------------------------------------------------------------
extern "C" void kernel_launch(void* const* d_in, const int* in_sizes, int n_in,
                              void* d_out, int out_size, void* d_ws, size_t ws_size,
                              hipStream_t stream) {
  const float* node_tab = (const float*)d_in[0];
  const float* edge_tab = (const float*)d_in[1];
  const float* c1_w  = (const float*)d_in[2];
  const float* c1_we = (const float*)d_in[3];
  const float* c1_as = (const float*)d_in[4];
  const float* c1_ad = (const float*)d_in[5];
  const float* c1_ae = (const float*)d_in[6];
  const float* c1_b  = (const float*)d_in[7];
  const float* c2_w  = (const float*)d_in[8];
  const float* c2_we = (const float*)d_in[9];
  const float* c2_as = (const float*)d_in[10];
  const float* c2_ad = (const float*)d_in[11];
  const float* c2_ae = (const float*)d_in[12];
  const float* c2_b  = (const float*)d_in[13];
  const float* s_w1  = (const float*)d_in[14];
  const float* s_b1  = (const float*)d_in[15];
  const float* s_w2  = (const float*)d_in[16];
  const float* s_b2  = (const float*)d_in[17];
  const float* n_w1  = (const float*)d_in[18];
  const float* n_b1  = (const float*)d_in[19];
  const float* n_w2  = (const float*)d_in[20];
  const float* n_b2  = (const float*)d_in[21];
  const float* e_w1  = (const float*)d_in[22];
  const float* e_b1  = (const float*)d_in[23];
  const float* e_w2  = (const float*)d_in[24];
  const float* e_b2  = (const float*)d_in[25];
  const int* x    = (const int*)d_in[26];
  const int* ei   = (const int*)d_in[27];
  const int* ea   = (const int*)d_in[28];
  const int* nedg = (const int*)d_in[29];
  float* out = (float*)d_out;

  graph_kernel<<<dim3(B_GR), dim3(256), 0, stream>>>(
      node_tab, edge_tab, c1_w, c1_we, c1_as, c1_ad, c1_ae, c1_b,
      c2_w, c2_we, c2_as, c2_ad, c2_ae, c2_b,
      s_w1, s_b1, s_w2, s_b2, n_w1, n_b1, n_w2, n_b2,
      e_w1, e_b1, e_w2, e_b2, x, ei, ea, nedg, out);
}

// Round 4
// 358.365 us; speedup vs baseline: 1.9200x; 1.9200x over previous
//
#include <hip/hip_runtime.h>

// ---------------------------------------------------------------------------
// GNN action-value net, MI355X. Round 4: occupancy + de-serialization.
//  * prep_kernel -> __device__ g_tab: nt1=node_tab@c1_w (layer-1 matmul becomes
//    a gather), per-category attn scalars, per-edge-type logit constants,
//    n_w2 padded 128x104 (float4-loadable).
//  * graph_kernel: 1 block/graph, 256 thr. LDS ~79KB -> 2 blocks/CU.
//    Edge-parallel softmax (LDS atomicMax/fadd), wave-scan CSR, CSR reused
//    across both GAT layers, attn scalars via matmul epilogue atomics.
// ---------------------------------------------------------------------------

#define NPG 64
#define DEG 16
#define EPG 1024
#define NEPG 256
#define B_GR 1024
#define E_TOT 1048576
#define EMB 64
#define HID 128
#define NOUT 101
#define OUT_PG 6721            // 1 + 64*101 + 256
#define SROW 132               // padded LDS row stride (floats)

// g_tab layout (floats)
#define T_NT1   0              // 100x128 (12800)
#define T_HS1   12800          // 128 (100 used)
#define T_HD1   12928          // 128
#define T_HE1   13056          // 16 (4 used)
#define T_HE2   13072          // 16
#define T_NW2P  13088          // 128x104 (13312), cols 101..103 = 0
#define T_TOTAL (13088 + 13312)

__device__ float g_tab[T_TOTAL];

__device__ __forceinline__ unsigned mono(float f) {
  unsigned u = __float_as_uint(f);
  return (u & 0x80000000u) ? ~u : (u | 0x80000000u);
}
__device__ __forceinline__ float demono(unsigned k) {
  return (k & 0x80000000u) ? __uint_as_float(k ^ 0x80000000u) : __uint_as_float(~k);
}

// ---------------------------------------------------------------------------
__global__ void prep_kernel(
    const float* __restrict__ node_tab, const float* __restrict__ edge_tab,
    const float* __restrict__ c1_w,  const float* __restrict__ c1_we,
    const float* __restrict__ c1_as, const float* __restrict__ c1_ad,
    const float* __restrict__ c1_ae,
    const float* __restrict__ c2_we, const float* __restrict__ c2_ae,
    const float* __restrict__ n_w2)
{
  const int b = blockIdx.x, tid = threadIdx.x;
  if (b < 50) {                       // nt1 = node_tab @ c1_w  (100x128)
    const int idx = b * 256 + tid;
    const int i = idx >> 7, j = idx & (HID - 1);
    float s = 0.f;
    #pragma unroll 8
    for (int k = 0; k < EMB; ++k) s = fmaf(node_tab[i*EMB + k], c1_w[k*HID + j], s);
    g_tab[T_NT1 + idx] = s;
  } else if (b == 50) {               // per-category attention scalars
    __shared__ float vs[EMB], vd[EMB];
    if (tid < EMB) {
      float a = 0.f, d = 0.f;
      for (int j = 0; j < HID; ++j) {
        const float w = c1_w[tid*HID + j];
        a = fmaf(w, c1_as[j], a); d = fmaf(w, c1_ad[j], d);
      }
      vs[tid] = a; vd[tid] = d;
    }
    __syncthreads();
    if (tid < 128) {
      float a = 0.f, d = 0.f;
      if (tid < 100) {
        for (int k = 0; k < EMB; ++k) {
          const float xv = node_tab[tid*EMB + k];
          a = fmaf(xv, vs[k], a); d = fmaf(xv, vd[k], d);
        }
      }
      g_tab[T_HS1 + tid] = a; g_tab[T_HD1 + tid] = d;
    }
  } else if (b == 51) {               // per-edge-type logit constants
    __shared__ float v1[EMB], v2[EMB];
    if (tid < EMB) {
      float a = 0.f, d = 0.f;
      for (int j = 0; j < HID; ++j) {
        a = fmaf(c1_we[tid*HID + j], c1_ae[j], a);
        d = fmaf(c2_we[tid*HID + j], c2_ae[j], d);
      }
      v1[tid] = a; v2[tid] = d;
    }
    __syncthreads();
    if (tid < 16) {
      float a = 0.f, d = 0.f;
      if (tid < 4)
        for (int k = 0; k < EMB; ++k) {
          const float ev = edge_tab[tid*EMB + k];
          a = fmaf(ev, v1[k], a); d = fmaf(ev, v2[k], d);
        }
      g_tab[T_HE1 + tid] = a; g_tab[T_HE2 + tid] = d;
    }
  } else {                            // n_w2 padded to 128x104
    for (int i = tid; i < HID*104; i += 256) {
      const int k = i / 104, o = i - k*104;
      g_tab[T_NW2P + i] = (o < NOUT) ? n_w2[k*NOUT + o] : 0.f;
    }
  }
}

// ---------------------------------------------------------------------------
// C[64x128] = A[64x128] @ Bw[128x128] (+bias)(relu). 16x16 thr, 4r x 8c each.
// SCAL: also ns[r] += sum_c C[r][c]*asv[c], nd likewise (attn scalar fusion).
template<bool RELU, bool BIAS, bool SCAL>
__device__ __forceinline__ void mm128(const float* __restrict__ A,
                                      const float* __restrict__ Bw,
                                      const float* __restrict__ bias,
                                      float* __restrict__ C,
                                      const float* __restrict__ asv,
                                      const float* __restrict__ adv,
                                      float* __restrict__ ns, float* __restrict__ nd,
                                      int tid)
{
  const int r0 = (tid >> 4) * 4;
  const int c0 = (tid & 15) * 8;
  float acc[4][8] = {};
  #pragma unroll 4
  for (int k = 0; k < HID; ++k) {
    const float4 b0 = *(const float4*)(Bw + k*HID + c0);
    const float4 b1 = *(const float4*)(Bw + k*HID + c0 + 4);
    const float bv[8] = {b0.x,b0.y,b0.z,b0.w,b1.x,b1.y,b1.z,b1.w};
    float av[4];
    #pragma unroll
    for (int i = 0; i < 4; ++i) av[i] = A[(r0+i)*SROW + k];
    #pragma unroll
    for (int i = 0; i < 4; ++i)
      #pragma unroll
      for (int j = 0; j < 8; ++j) acc[i][j] = fmaf(av[i], bv[j], acc[i][j]);
  }
  float asr[8], adr[8];
  if (SCAL) {
    const float4 a0 = *(const float4*)(asv + c0), a1 = *(const float4*)(asv + c0 + 4);
    const float4 d0 = *(const float4*)(adv + c0), d1 = *(const float4*)(adv + c0 + 4);
    asr[0]=a0.x;asr[1]=a0.y;asr[2]=a0.z;asr[3]=a0.w;asr[4]=a1.x;asr[5]=a1.y;asr[6]=a1.z;asr[7]=a1.w;
    adr[0]=d0.x;adr[1]=d0.y;adr[2]=d0.z;adr[3]=d0.w;adr[4]=d1.x;adr[5]=d1.y;adr[6]=d1.z;adr[7]=d1.w;
  }
  #pragma unroll
  for (int i = 0; i < 4; ++i) {
    float pa = 0.f, pd = 0.f;
    #pragma unroll
    for (int j = 0; j < 8; ++j) {
      float v = acc[i][j];
      if (BIAS) v += bias[c0+j];
      if (RELU) v = fmaxf(v, 0.f);
      C[(r0+i)*SROW + c0 + j] = v;
      if (SCAL) { pa = fmaf(v, asr[j], pa); pd = fmaf(v, adr[j], pd); }
    }
    if (SCAL) { atomicAdd(&ns[r0+i], pa); atomicAdd(&nd[r0+i], pd); }
  }
}

// ---------------------------------------------------------------------------
__global__ __launch_bounds__(256, 2) void graph_kernel(
    const float* __restrict__ c1_b,
    const float* __restrict__ c2_w,  const float* __restrict__ c2_as,
    const float* __restrict__ c2_ad, const float* __restrict__ c2_b,
    const float* __restrict__ s_w1,  const float* __restrict__ s_b1,
    const float* __restrict__ s_w2,  const float* __restrict__ s_b2,
    const float* __restrict__ n_w1,  const float* __restrict__ n_b1,
    const float* __restrict__ n_b2,
    const float* __restrict__ e_w1,  const float* __restrict__ e_b1,
    const float* __restrict__ e_w2,  const float* __restrict__ e_b2,
    const int* __restrict__ x,  const int* __restrict__ ei,
    const int* __restrict__ ea, const int* __restrict__ nedg,
    float* __restrict__ out)
{
  const int gid = blockIdx.x;
  const int tid = threadIdx.x;
  const int nb = gid * NPG;
  const int ebase = gid * EPG;

  __shared__ __align__(16) float bufA[NPG*SROW];   // 33792B
  __shared__ __align__(16) float bufB[NPG*SROW];   // 33792B
  __shared__ float lg[EPG];                        // 4096B logits -> exp()
  __shared__ unsigned short csr[EPG];              // 2048B
  __shared__ unsigned topo[EPG];                   // 4096B src|dst<<8|et<<16
  __shared__ int xs[NPG], cnt[NPG], cofs[NPG+1], cpos[NPG];
  __shared__ unsigned mkey[NPG];
  __shared__ float den[NPG], mval[NPG], ns[NPG], nd[NPG];
  __shared__ float gp[HID], zh[HID];
  __shared__ float hc1[4], hc2[4];

  // ---- P0: topology + tables ----
  for (int k = tid; k < EPG; k += 256) {
    const unsigned s = (unsigned)(ei[ebase + k] - nb);
    const unsigned d = (unsigned)(ei[E_TOT + ebase + k] - nb);
    const unsigned t = (unsigned)ea[ebase + k];
    topo[k] = s | (d << 8) | (t << 16);
  }
  if (tid < NPG) { xs[tid] = x[nb + tid]; cnt[tid] = 0; mkey[tid] = 0u; den[tid] = 0.f; }
  if (tid < 4) { hc1[tid] = g_tab[T_HE1 + tid]; hc2[tid] = g_tab[T_HE2 + tid]; }
  __syncthreads();

  // ---- P1: gather h1pre rows (nt1) + per-node attn scalars ----
  for (int idx = tid; idx < NPG*32; idx += 256) {
    const int n = idx >> 5, q = (idx & 31) * 4;
    *(float4*)(bufA + n*SROW + q) = *(const float4*)(g_tab + T_NT1 + xs[n]*HID + q);
  }
  if (tid < NPG) { const int c = xs[tid]; ns[tid] = g_tab[T_HS1 + c]; nd[tid] = g_tab[T_HD1 + c]; }
  __syncthreads();

  // ---- P2: layer-1 logits, degree count, segment max ----
  for (int k = tid; k < EPG; k += 256) {
    const unsigned tp = topo[k];
    const int s = tp & 255, d = (tp >> 8) & 255, t = tp >> 16;
    float l = ns[s] + nd[d] + hc1[t];
    l = (l > 0.f) ? l : 0.2f * l;
    lg[k] = l;
    atomicAdd(&cnt[d], 1);
    atomicMax(&mkey[d], mono(l));
  }
  __syncthreads();

  // ---- P3: wave-0 scan -> cofs/cpos; extract max; zero ns/nd for layer 2 ----
  if (tid < 64) {
    const int c = cnt[tid];
    int v = c;
    #pragma unroll
    for (int off = 1; off < 64; off <<= 1) {
      const int up = __shfl_up(v, off, 64);
      if (tid >= off) v += up;
    }
    cofs[tid+1] = v;
    cpos[tid] = v - c;
    if (tid == 0) cofs[0] = 0;
  } else if (tid < 128) {
    mval[tid-64] = demono(mkey[tid-64]);
  } else if (tid < 192) {
    ns[tid-128] = 0.f; nd[tid-128] = 0.f;
  }
  __syncthreads();

  // ---- P4: exp + denominators + CSR build; re-zero mkey for layer 2 ----
  for (int k = tid; k < EPG; k += 256) {
    const int d = (topo[k] >> 8) & 255;
    const int p = atomicAdd(&cpos[d], 1);
    csr[p] = (unsigned short)k;
    const float ex = __expf(lg[k] - mval[d]);
    lg[k] = ex;
    atomicAdd(&den[d], ex);
  }
  if (tid < NPG) mkey[tid] = 0u;
  __syncthreads();

  // ---- P5: layer-1 scatter: h1 = relu(inv*sum(ex*h1pre[src]) + c1_b) ----
  {
    const int n  = tid >> 2;
    const int cb = (tid & 3) * 32;
    float4 acc[8] = {};
    const int s = cofs[n], e = cofs[n+1];
    const float inv = 1.f / (den[n] + 1e-16f);
    for (int i = s; i < e; ++i) {
      const int k = csr[i];
      const float a = lg[k];
      const float4* hp = (const float4*)(bufA + (topo[k] & 255)*SROW + cb);
      #pragma unroll
      for (int q = 0; q < 8; ++q) {
        const float4 h = hp[q];
        acc[q].x = fmaf(a, h.x, acc[q].x); acc[q].y = fmaf(a, h.y, acc[q].y);
        acc[q].z = fmaf(a, h.z, acc[q].z); acc[q].w = fmaf(a, h.w, acc[q].w);
      }
    }
    #pragma unroll
    for (int q = 0; q < 8; ++q) {
      float4 v = acc[q];
      v.x = fmaxf(fmaf(v.x, inv, c1_b[cb+q*4+0]), 0.f);
      v.y = fmaxf(fmaf(v.y, inv, c1_b[cb+q*4+1]), 0.f);
      v.z = fmaxf(fmaf(v.z, inv, c1_b[cb+q*4+2]), 0.f);
      v.w = fmaxf(fmaf(v.w, inv, c1_b[cb+q*4+3]), 0.f);
      *(float4*)(bufB + n*SROW + cb + q*4) = v;
    }
  }
  __syncthreads();

  // ---- P6: h2pre = h1 @ c2_w, fused attn scalars; re-zero den ----
  if (tid < NPG) den[tid] = 0.f;
  mm128<false,false,true>(bufB, c2_w, nullptr, bufA, c2_as, c2_ad, ns, nd, tid);
  __syncthreads();

  // ---- P7: layer-2 logits + segment max (CSR reused) ----
  for (int k = tid; k < EPG; k += 256) {
    const unsigned tp = topo[k];
    const int s = tp & 255, d = (tp >> 8) & 255, t = tp >> 16;
    float l = ns[s] + nd[d] + hc2[t];
    l = (l > 0.f) ? l : 0.2f * l;
    lg[k] = l;
    atomicMax(&mkey[d], mono(l));
  }
  __syncthreads();
  if (tid < NPG) mval[tid] = demono(mkey[tid]);
  __syncthreads();

  // ---- P8: exp + denominators ----
  for (int k = tid; k < EPG; k += 256) {
    const int d = (topo[k] >> 8) & 255;
    const float ex = __expf(lg[k] - mval[d]);
    lg[k] = ex;
    atomicAdd(&den[d], ex);
  }
  __syncthreads();

  // ---- P9: layer-2 scatter: h2 = inv*sum(ex*h2pre[src]) + c2_b ----
  {
    const int n  = tid >> 2;
    const int cb = (tid & 3) * 32;
    float4 acc[8] = {};
    const int s = cofs[n], e = cofs[n+1];
    const float inv = 1.f / (den[n] + 1e-16f);
    for (int i = s; i < e; ++i) {
      const int k = csr[i];
      const float a = lg[k];
      const float4* hp = (const float4*)(bufA + (topo[k] & 255)*SROW + cb);
      #pragma unroll
      for (int q = 0; q < 8; ++q) {
        const float4 h = hp[q];
        acc[q].x = fmaf(a, h.x, acc[q].x); acc[q].y = fmaf(a, h.y, acc[q].y);
        acc[q].z = fmaf(a, h.z, acc[q].z); acc[q].w = fmaf(a, h.w, acc[q].w);
      }
    }
    #pragma unroll
    for (int q = 0; q < 8; ++q) {
      float4 v = acc[q];
      v.x = fmaf(v.x, inv, c2_b[cb+q*4+0]);
      v.y = fmaf(v.y, inv, c2_b[cb+q*4+1]);
      v.z = fmaf(v.z, inv, c2_b[cb+q*4+2]);
      v.w = fmaf(v.w, inv, c2_b[cb+q*4+3]);
      *(float4*)(bufB + n*SROW + cb + q*4) = v;   // h2 -> bufB
    }
  }
  __syncthreads();

  // ---- P10: pooling + stop head ----
  if (tid < HID) {
    float s = 0.f;
    for (int n2 = 0; n2 < NPG; ++n2) s += bufB[n2*SROW + tid];
    gp[tid] = s;
  }
  __syncthreads();
  if (tid < HID) {
    float a = s_b1[tid];
    for (int c = 0; c < HID; ++c) a = fmaf(gp[c], s_w1[c*HID + tid], a);
    zh[tid] = fmaxf(a, 0.f);
  }
  __syncthreads();
  if (tid < 64) {
    float p = fmaf(zh[tid], s_w2[tid], zh[tid+64]*s_w2[tid+64]);
    #pragma unroll
    for (int off = 32; off > 0; off >>= 1) p += __shfl_down(p, off, 64);
    if (tid == 0) out[(size_t)gid*OUT_PG] = p + s_b2[0];
  }
  __syncthreads();

  // ---- P11: addnode head ----
  mm128<true,true,false>(bufB, n_w1, n_b1, bufA, nullptr, nullptr, nullptr, nullptr, tid);
  __syncthreads();
  if (tid < 208) {          // 16 row-tiles x 13 col-tiles (104 padded cols)
    const int rt = tid / 13, ct = tid - rt*13;
    const int r0 = rt*4, c0 = ct*8;
    float acc[4][8] = {};
    #pragma unroll 4
    for (int k = 0; k < HID; ++k) {
      const float4 b0 = *(const float4*)(g_tab + T_NW2P + k*104 + c0);
      const float4 b1 = *(const float4*)(g_tab + T_NW2P + k*104 + c0 + 4);
      const float bv[8] = {b0.x,b0.y,b0.z,b0.w,b1.x,b1.y,b1.z,b1.w};
      float av[4];
      #pragma unroll
      for (int i = 0; i < 4; ++i) av[i] = bufA[(r0+i)*SROW + k];
      #pragma unroll
      for (int i = 0; i < 4; ++i)
        #pragma unroll
        for (int j = 0; j < 8; ++j) acc[i][j] = fmaf(av[i], bv[j], acc[i][j]);
    }
    const size_t ob = (size_t)gid*OUT_PG + 1;
    #pragma unroll
    for (int i = 0; i < 4; ++i) {
      #pragma unroll
      for (int j = 0; j < 8; ++j) {
        const int o = c0 + j;
        if (o < NOUT) out[ob + (size_t)(r0+i)*NOUT + o] = acc[i][j] + n_b2[o];
      }
    }
  }
  __syncthreads();

  // ---- P12: addedge head ----
  mm128<false,false,false>(bufB, e_w1, nullptr, bufA, nullptr, nullptr, nullptr, nullptr, tid);
  __syncthreads();
  {
    const int r = gid*NEPG + tid;
    const int i = nedg[2*r]     - nb;
    const int j = nedg[2*r + 1] - nb;
    const float* ui = bufA + i*SROW;
    const float* uj = bufA + j*SROW;
    float s = 0.f;
    for (int c = 0; c < HID; ++c) {
      float v = ui[c] + uj[c] + e_b1[c];
      v = fmaxf(v, 0.f);
      s = fmaf(v, e_w2[c], s);
    }
    out[(size_t)gid*OUT_PG + 1 + NPG*NOUT + tid] = s + e_b2[0];
  }
}

// ---------------------------------------------------------------------------
extern "C" void kernel_launch(void* const* d_in, const int* in_sizes, int n_in,
                              void* d_out, int out_size, void* d_ws, size_t ws_size,
                              hipStream_t stream) {
  const float* node_tab = (const float*)d_in[0];
  const float* edge_tab = (const float*)d_in[1];
  const float* c1_w  = (const float*)d_in[2];
  const float* c1_we = (const float*)d_in[3];
  const float* c1_as = (const float*)d_in[4];
  const float* c1_ad = (const float*)d_in[5];
  const float* c1_ae = (const float*)d_in[6];
  const float* c1_b  = (const float*)d_in[7];
  const float* c2_w  = (const float*)d_in[8];
  const float* c2_we = (const float*)d_in[9];
  const float* c2_as = (const float*)d_in[10];
  const float* c2_ad = (const float*)d_in[11];
  const float* c2_ae = (const float*)d_in[12];
  const float* c2_b  = (const float*)d_in[13];
  const float* s_w1  = (const float*)d_in[14];
  const float* s_b1  = (const float*)d_in[15];
  const float* s_w2  = (const float*)d_in[16];
  const float* s_b2  = (const float*)d_in[17];
  const float* n_w1  = (const float*)d_in[18];
  const float* n_b1  = (const float*)d_in[19];
  const float* n_w2  = (const float*)d_in[20];
  const float* n_b2  = (const float*)d_in[21];
  const float* e_w1  = (const float*)d_in[22];
  const float* e_b1  = (const float*)d_in[23];
  const float* e_w2  = (const float*)d_in[24];
  const float* e_b2  = (const float*)d_in[25];
  const int* x    = (const int*)d_in[26];
  const int* ei   = (const int*)d_in[27];
  const int* ea   = (const int*)d_in[28];
  const int* nedg = (const int*)d_in[29];
  float* out = (float*)d_out;

  prep_kernel<<<dim3(53), dim3(256), 0, stream>>>(
      node_tab, edge_tab, c1_w, c1_we, c1_as, c1_ad, c1_ae,
      c2_we, c2_ae, n_w2);

  graph_kernel<<<dim3(B_GR), dim3(256), 0, stream>>>(
      c1_b, c2_w, c2_as, c2_ad, c2_b,
      s_w1, s_b1, s_w2, s_b2, n_w1, n_b1, n_b2,
      e_w1, e_b1, e_w2, e_b2, x, ei, ea, nedg, out);
}

// Round 5
// 221.285 us; speedup vs baseline: 3.1094x; 1.6195x over previous
//
#include <hip/hip_runtime.h>

// ---------------------------------------------------------------------------
// GNN action-value net, MI355X. Round 5: MFMA rewrite.
//  * All matmul-shaped work on v_mfma_f32_16x16x32_bf16:
//      - h2pre = h1 @ c2_w, a1 = relu(h2@n_w1+b), u = h2@e_w1, addnode head
//      - BOTH GAT aggregations: dense normalized alpha matrix P (64x64) built
//        in LDS (atomicAdd exp, normalized at bf16-convert), then P @ H.
//  * prep_kernel packs weights into per-lane MFMA B-fragment order (one
//    coalesced 16B load / lane / MFMA), builds nt1 table (layer-1 matmul is
//    a gather), per-category + per-edge-type attention scalars, s_w1^T.
//  * LDS ~51.7KB -> 3 blocks/CU. Strides 136/72 (ushort) are bank-balanced
//    for ds_read_b128 fragments.
// Fragment maps (verified, learn_hip m89/m91/m120):
//   A[m][k]: m=lane&15, k=(lane>>4)*8+j   B[k][n]: n=lane&15, k=(lane>>4)*8+j
//   C/D:     col=lane&15, row=(lane>>4)*4+reg
// ---------------------------------------------------------------------------

#define NPG 64
#define EPG 1024
#define NEPG 256
#define B_GR 1024
#define E_TOT 1048576
#define EMB 64
#define HID 128
#define NOUT 101
#define OUT_PG 6721            // 1 + 64*101 + 256

typedef __attribute__((ext_vector_type(8))) short bf16x8;
typedef __attribute__((ext_vector_type(4))) float f32x4;
typedef unsigned short ushort_t;

__device__ ushort_t g_nt1[100*HID];      // bf16 rows: node_tab @ c1_w
__device__ ushort_t g_c2w[HID*HID];      // frag-packed bf16
__device__ ushort_t g_nw1[HID*HID];
__device__ ushort_t g_ew1[HID*HID];
__device__ ushort_t g_nw2[HID*112];      // N padded 101 -> 112
__device__ float    g_sw1t[HID*HID];     // s_w1 transposed, f32
__device__ float    g_hs1[128], g_hd1[128], g_he1[4], g_he2[4];

__device__ __forceinline__ ushort_t f2bf(float f) {
  unsigned u = __float_as_uint(f);
  return (ushort_t)((u + 0x7fffu + ((u >> 16) & 1u)) >> 16);
}
__device__ __forceinline__ float bf2f(ushort_t h) {
  return __uint_as_float(((unsigned)h) << 16);
}
__device__ __forceinline__ unsigned mono(float f) {
  unsigned u = __float_as_uint(f);
  return (u & 0x80000000u) ? ~u : (u | 0x80000000u);
}
__device__ __forceinline__ float demono(unsigned k) {
  return (k & 0x80000000u) ? __uint_as_float(k ^ 0x80000000u) : __uint_as_float(~k);
}

// ---------------------------------------------------------------------------
__global__ void prep_kernel(
    const float* __restrict__ node_tab, const float* __restrict__ edge_tab,
    const float* __restrict__ c1_w,  const float* __restrict__ c1_we,
    const float* __restrict__ c1_as, const float* __restrict__ c1_ad,
    const float* __restrict__ c1_ae,
    const float* __restrict__ c2_w,  const float* __restrict__ c2_we,
    const float* __restrict__ c2_ae,
    const float* __restrict__ s_w1,  const float* __restrict__ n_w1,
    const float* __restrict__ n_w2,  const float* __restrict__ e_w1)
{
  const int b = blockIdx.x, tid = threadIdx.x;
  if (b < 50) {                       // nt1 = node_tab @ c1_w (100x128) -> bf16
    const int idx = b * 256 + tid;
    const int i = idx >> 7, j = idx & (HID - 1);
    float s = 0.f;
    #pragma unroll 8
    for (int k = 0; k < EMB; ++k) s = fmaf(node_tab[i*EMB + k], c1_w[k*HID + j], s);
    g_nt1[idx] = f2bf(s);
  } else if (b == 50) {               // per-category attention scalars (f32)
    __shared__ float vs[EMB], vd[EMB];
    if (tid < EMB) {
      float a = 0.f, d = 0.f;
      for (int j = 0; j < HID; ++j) {
        const float w = c1_w[tid*HID + j];
        a = fmaf(w, c1_as[j], a); d = fmaf(w, c1_ad[j], d);
      }
      vs[tid] = a; vd[tid] = d;
    }
    __syncthreads();
    if (tid < 128) {
      float a = 0.f, d = 0.f;
      if (tid < 100) {
        for (int k = 0; k < EMB; ++k) {
          const float xv = node_tab[tid*EMB + k];
          a = fmaf(xv, vs[k], a); d = fmaf(xv, vd[k], d);
        }
      }
      g_hs1[tid] = a; g_hd1[tid] = d;
    }
  } else if (b == 51) {               // per-edge-type logit constants
    __shared__ float v1[EMB], v2[EMB];
    if (tid < EMB) {
      float a = 0.f, d = 0.f;
      for (int j = 0; j < HID; ++j) {
        a = fmaf(c1_we[tid*HID + j], c1_ae[j], a);
        d = fmaf(c2_we[tid*HID + j], c2_ae[j], d);
      }
      v1[tid] = a; v2[tid] = d;
    }
    __syncthreads();
    if (tid < 4) {
      float a = 0.f, d = 0.f;
      for (int k = 0; k < EMB; ++k) {
        const float ev = edge_tab[tid*EMB + k];
        a = fmaf(ev, v1[k], a); d = fmaf(ev, v2[k], d);
      }
      g_he1[tid] = a; g_he2[tid] = d;
    }
  } else if (b >= 52 && b <= 54) {    // pack 128x128 weights into frag order
    const float* W = (b == 52) ? c2_w : (b == 53) ? n_w1 : e_w1;
    ushort_t* G = (b == 52) ? g_c2w : (b == 53) ? g_nw1 : g_ew1;
    for (int idx = tid; idx < HID*HID; idx += 256) {
      const int j = idx & 7, l = (idx >> 3) & 63, r2 = idx >> 9;
      const int ks = r2 & 3, ct = r2 >> 2;
      const int row = ks*32 + (l >> 4)*8 + j;
      const int col = ct*16 + (l & 15);
      G[idx] = f2bf(W[row*HID + col]);
    }
  } else if (b == 55) {               // pack n_w2 (128x101 -> 128x112)
    for (int idx = tid; idx < HID*112; idx += 256) {
      const int j = idx & 7, l = (idx >> 3) & 63, r2 = idx >> 9;
      const int ks = r2 & 3, ct = r2 >> 2;     // ct 0..6
      const int row = ks*32 + (l >> 4)*8 + j;
      const int col = ct*16 + (l & 15);
      g_nw2[idx] = (col < NOUT) ? f2bf(n_w2[row*NOUT + col]) : (ushort_t)0;
    }
  } else {                            // b == 56: s_w1 transpose (f32)
    for (int idx = tid; idx < HID*HID; idx += 256)
      g_sw1t[idx] = s_w1[(idx & 127)*HID + (idx >> 7)];
  }
}

// ---------------------------------------------------------------------------
#define S_HC 0          // 128 x 72 ushort, col-major (feat,node)   18432B
#define S_HR 18432      // 64 x 136 ushort, row-major               17408B
#define S_PF 18432      // overlay: 64x64 f32 (P build)             16384B
#define S_PB 35840      // 64 x 72 ushort (P bf16)                  9216B
#define S_LG 45056      // 1024 ushort (bf16 logits)                2048B
#define S_TP 47104      // 1024 ushort (topo)                       2048B
#define S_MK 49152      // 64 u32
#define S_DEN 49408     // 64 f32
#define S_MV 49664      // 64 f32 (max, then inv)
#define S_NS 49920      // 64 f32
#define S_ND 50176      // 64 f32
#define S_XS 50432      // 64 int
#define S_GP 50688      // 128 f32 (pool; later e_b1)
#define S_ZH 51200      // 128 f32 (stop hidden; later e_w2)
#define S_HCC 51712     // 8 f32
#define S_TOT 51744

__global__ __launch_bounds__(256, 3) void graph_kernel(
    const float* __restrict__ c1_b,
    const float* __restrict__ c2_as, const float* __restrict__ c2_ad,
    const float* __restrict__ c2_b,
    const float* __restrict__ s_b1,  const float* __restrict__ s_w2,
    const float* __restrict__ s_b2,
    const float* __restrict__ n_b1,  const float* __restrict__ n_b2,
    const float* __restrict__ e_b1,  const float* __restrict__ e_w2,
    const float* __restrict__ e_b2,
    const int* __restrict__ x,  const int* __restrict__ ei,
    const int* __restrict__ ea, const int* __restrict__ nedg,
    float* __restrict__ out)
{
  const int tid = threadIdx.x;
  const int gid = blockIdx.x;
  const int nb = gid * NPG;
  const int lane = tid & 63;
  const int wv = tid >> 6;
  const int qd = lane >> 4;
  const int cl = lane & 15;
  const int rb = wv * 16;

  __shared__ __align__(16) char smem[S_TOT];
  ushort_t* Hc   = (ushort_t*)(smem + S_HC);
  ushort_t* Hr   = (ushort_t*)(smem + S_HR);
  float*    Pf   = (float*)   (smem + S_PF);
  ushort_t* Pb   = (ushort_t*)(smem + S_PB);
  ushort_t* lgu  = (ushort_t*)(smem + S_LG);
  ushort_t* topo = (ushort_t*)(smem + S_TP);
  unsigned* mkey = (unsigned*)(smem + S_MK);
  float*    den  = (float*)   (smem + S_DEN);
  float*    mvi  = (float*)   (smem + S_MV);
  float*    ns   = (float*)   (smem + S_NS);
  float*    nd   = (float*)   (smem + S_ND);
  int*      xs   = (int*)     (smem + S_XS);
  float*    gp   = (float*)   (smem + S_GP);
  float*    zh   = (float*)   (smem + S_ZH);
  float*    hc   = (float*)   (smem + S_HCC);

  // ---- P0: topology, tables, zero-init ----
  for (int k = tid; k < EPG; k += 256) {
    const int s = ei[gid*EPG + k] - nb;
    const int d = ei[E_TOT + gid*EPG + k] - nb;
    const int t = ea[gid*EPG + k];
    topo[k] = (ushort_t)(s | (d << 6) | (t << 12));
  }
  if (tid < NPG) { xs[tid] = x[nb + tid]; mkey[tid] = 0u; den[tid] = 0.f; }
  if (tid >= 64 && tid < 72) hc[tid-64] = (tid < 68) ? g_he1[tid-64] : g_he2[tid-68];
  if (tid >= 128) gp[tid-128] = 0.f;
  __syncthreads();

  // ---- P1: gather h1pre col-major into Hc + per-node attn scalars ----
  {
    const int n = tid >> 2;
    const int f0 = (tid & 3) * 32;
    const ushort_t* src = g_nt1 + xs[n]*HID + f0;
    #pragma unroll
    for (int i = 0; i < 4; ++i) {
      bf16x8 v = *(const bf16x8*)(src + i*8);
      #pragma unroll
      for (int j = 0; j < 8; ++j) Hc[(f0 + i*8 + j)*72 + n] = (ushort_t)v[j];
    }
  }
  if (tid < NPG) { ns[tid] = g_hs1[xs[tid]]; nd[tid] = g_hd1[xs[tid]]; }
  __syncthreads();

  // ================= layer-1 softmax -> P =================
  for (int k = tid; k < EPG; k += 256) {
    const int tp = topo[k];
    const int s = tp & 63, d = (tp >> 6) & 63, t = tp >> 12;
    float l = ns[s] + nd[d] + hc[t];
    l = (l > 0.f) ? l : 0.2f * l;
    lgu[k] = f2bf(l);
    atomicMax(&mkey[d], mono(l));
  }
  __syncthreads();
  if (tid < NPG) mvi[tid] = demono(mkey[tid]);
  for (int i = tid; i < 4096; i += 256) Pf[i] = 0.f;
  __syncthreads();
  for (int k = tid; k < EPG; k += 256) {
    const int tp = topo[k];
    const int s = tp & 63, d = (tp >> 6) & 63;
    const float ex = __expf(bf2f(lgu[k]) - mvi[d]);
    atomicAdd(&den[d], ex);
    atomicAdd(&Pf[d*64 + s], ex);
  }
  __syncthreads();
  if (tid < NPG) mvi[tid] = 1.f / (den[tid] + 1e-16f);
  __syncthreads();
  for (int i = tid; i < 4096; i += 256) {
    const int m = i >> 6, kk = i & 63;
    Pb[m*72 + kk] = f2bf(Pf[i] * mvi[m]);
  }
  if (tid < NPG) { mkey[tid] = 0u; den[tid] = 0.f; }   // prep layer 2
  __syncthreads();

  // ---- agg1 (MFMA): h1 = relu(P @ h1pre + c1_b) -> Hr ----
  {
    const bf16x8 a0 = *(const bf16x8*)(Pb + (rb+cl)*72 + qd*8);
    const bf16x8 a1 = *(const bf16x8*)(Pb + (rb+cl)*72 + 32 + qd*8);
    #pragma unroll
    for (int ct = 0; ct < 8; ++ct) {
      f32x4 acc = {0.f, 0.f, 0.f, 0.f};
      const bf16x8 b0 = *(const bf16x8*)(Hc + (ct*16+cl)*72 + qd*8);
      const bf16x8 b1 = *(const bf16x8*)(Hc + (ct*16+cl)*72 + 32 + qd*8);
      acc = __builtin_amdgcn_mfma_f32_16x16x32_bf16(a0, b0, acc, 0, 0, 0);
      acc = __builtin_amdgcn_mfma_f32_16x16x32_bf16(a1, b1, acc, 0, 0, 0);
      const int n = ct*16 + cl;
      const float bias = c1_b[n];
      #pragma unroll
      for (int r = 0; r < 4; ++r)
        Hr[(rb + qd*4 + r)*136 + n] = f2bf(fmaxf(acc[r] + bias, 0.f));
    }
  }
  __syncthreads();

  // ---- h2pre = h1 @ c2_w (MFMA) -> Hc col-major, fused ns/nd ----
  {
    bf16x8 af[4];
    #pragma unroll
    for (int ks = 0; ks < 4; ++ks)
      af[ks] = *(const bf16x8*)(Hr + (rb+cl)*136 + ks*32 + qd*8);
    float pns[4] = {0.f,0.f,0.f,0.f}, pnd[4] = {0.f,0.f,0.f,0.f};
    #pragma unroll
    for (int ct = 0; ct < 8; ++ct) {
      f32x4 acc = {0.f, 0.f, 0.f, 0.f};
      #pragma unroll
      for (int ks = 0; ks < 4; ++ks) {
        const bf16x8 b = *(const bf16x8*)(g_c2w + ((ct*4+ks)*64 + lane)*8);
        acc = __builtin_amdgcn_mfma_f32_16x16x32_bf16(af[ks], b, acc, 0, 0, 0);
      }
      const int n = ct*16 + cl;
      const float asv = c2_as[n], adv = c2_ad[n];
      #pragma unroll
      for (int r = 0; r < 4; ++r) {
        const float v = acc[r];
        Hc[n*72 + (rb + qd*4 + r)] = f2bf(v);
        pns[r] = fmaf(v, asv, pns[r]);
        pnd[r] = fmaf(v, adv, pnd[r]);
      }
    }
    #pragma unroll
    for (int r = 0; r < 4; ++r) {
      #pragma unroll
      for (int off = 1; off < 16; off <<= 1) {
        pns[r] += __shfl_xor(pns[r], off, 64);
        pnd[r] += __shfl_xor(pnd[r], off, 64);
      }
    }
    if (cl == 0) {
      #pragma unroll
      for (int r = 0; r < 4; ++r) { ns[rb+qd*4+r] = pns[r]; nd[rb+qd*4+r] = pnd[r]; }
    }
  }
  __syncthreads();

  // ================= layer-2 softmax -> P =================
  for (int k = tid; k < EPG; k += 256) {
    const int tp = topo[k];
    const int s = tp & 63, d = (tp >> 6) & 63, t = tp >> 12;
    float l = ns[s] + nd[d] + hc[4 + t];
    l = (l > 0.f) ? l : 0.2f * l;
    lgu[k] = f2bf(l);
    atomicMax(&mkey[d], mono(l));
  }
  __syncthreads();
  if (tid < NPG) mvi[tid] = demono(mkey[tid]);
  for (int i = tid; i < 4096; i += 256) Pf[i] = 0.f;   // Hr(h1) is dead now
  __syncthreads();
  for (int k = tid; k < EPG; k += 256) {
    const int tp = topo[k];
    const int s = tp & 63, d = (tp >> 6) & 63;
    const float ex = __expf(bf2f(lgu[k]) - mvi[d]);
    atomicAdd(&den[d], ex);
    atomicAdd(&Pf[d*64 + s], ex);
  }
  __syncthreads();
  if (tid < NPG) mvi[tid] = 1.f / (den[tid] + 1e-16f);
  __syncthreads();
  for (int i = tid; i < 4096; i += 256) {
    const int m = i >> 6, kk = i & 63;
    Pb[m*72 + kk] = f2bf(Pf[i] * mvi[m]);
  }
  __syncthreads();

  // ---- agg2 (MFMA): h2 = P @ h2pre + c2_b -> Hr, fused pooling ----
  {
    const bf16x8 a0 = *(const bf16x8*)(Pb + (rb+cl)*72 + qd*8);
    const bf16x8 a1 = *(const bf16x8*)(Pb + (rb+cl)*72 + 32 + qd*8);
    #pragma unroll
    for (int ct = 0; ct < 8; ++ct) {
      f32x4 acc = {0.f, 0.f, 0.f, 0.f};
      const bf16x8 b0 = *(const bf16x8*)(Hc + (ct*16+cl)*72 + qd*8);
      const bf16x8 b1 = *(const bf16x8*)(Hc + (ct*16+cl)*72 + 32 + qd*8);
      acc = __builtin_amdgcn_mfma_f32_16x16x32_bf16(a0, b0, acc, 0, 0, 0);
      acc = __builtin_amdgcn_mfma_f32_16x16x32_bf16(a1, b1, acc, 0, 0, 0);
      const int n = ct*16 + cl;
      const float bias = c2_b[n];
      float colsum = 0.f;
      #pragma unroll
      for (int r = 0; r < 4; ++r) {
        const float v = acc[r] + bias;
        Hr[(rb + qd*4 + r)*136 + n] = f2bf(v);
        colsum += v;
      }
      colsum += __shfl_xor(colsum, 16, 64);
      colsum += __shfl_xor(colsum, 32, 64);
      if (qd == 0) atomicAdd(&gp[n], colsum);
    }
  }
  __syncthreads();

  // ---- stop head (f32, small) ----
  if (tid < HID) {
    float a = s_b1[tid];
    const float* wr = g_sw1t + tid*HID;
    #pragma unroll 4
    for (int c = 0; c < HID; ++c) a = fmaf(gp[c], wr[c], a);
    zh[tid] = fmaxf(a, 0.f);
  }
  __syncthreads();
  if (tid < 64) {
    float p = fmaf(zh[tid], s_w2[tid], zh[tid+64]*s_w2[tid+64]);
    #pragma unroll
    for (int off = 32; off > 0; off >>= 1) p += __shfl_down(p, off, 64);
    if (tid == 0) out[(size_t)gid*OUT_PG] = p + s_b2[0];
  }
  __syncthreads();

  // ---- addnode: a1 = relu(h2 @ n_w1 + n_b1) -> Hc region (row-major) ----
  ushort_t* a1b = Hc;   // reuse: 64 x 136
  {
    bf16x8 af[4];
    #pragma unroll
    for (int ks = 0; ks < 4; ++ks)
      af[ks] = *(const bf16x8*)(Hr + (rb+cl)*136 + ks*32 + qd*8);
    #pragma unroll
    for (int ct = 0; ct < 8; ++ct) {
      f32x4 acc = {0.f, 0.f, 0.f, 0.f};
      #pragma unroll
      for (int ks = 0; ks < 4; ++ks) {
        const bf16x8 b = *(const bf16x8*)(g_nw1 + ((ct*4+ks)*64 + lane)*8);
        acc = __builtin_amdgcn_mfma_f32_16x16x32_bf16(af[ks], b, acc, 0, 0, 0);
      }
      const int n = ct*16 + cl;
      const float bias = n_b1[n];
      #pragma unroll
      for (int r = 0; r < 4; ++r)
        a1b[(rb + qd*4 + r)*136 + n] = f2bf(fmaxf(acc[r] + bias, 0.f));
    }
  }
  __syncthreads();

  // ---- addnode head: out = a1 @ n_w2p + n_b2 ----
  {
    bf16x8 af[4];
    #pragma unroll
    for (int ks = 0; ks < 4; ++ks)
      af[ks] = *(const bf16x8*)(a1b + (rb+cl)*136 + ks*32 + qd*8);
    float* ob = out + (size_t)gid*OUT_PG + 1;
    #pragma unroll
    for (int ct = 0; ct < 7; ++ct) {
      f32x4 acc = {0.f, 0.f, 0.f, 0.f};
      #pragma unroll
      for (int ks = 0; ks < 4; ++ks) {
        const bf16x8 b = *(const bf16x8*)(g_nw2 + ((ct*4+ks)*64 + lane)*8);
        acc = __builtin_amdgcn_mfma_f32_16x16x32_bf16(af[ks], b, acc, 0, 0, 0);
      }
      const int o = ct*16 + cl;
      if (o < NOUT) {
        const float b2 = n_b2[o];
        #pragma unroll
        for (int r = 0; r < 4; ++r)
          ob[(size_t)(rb + qd*4 + r)*NOUT + o] = acc[r] + b2;
      }
    }
  }
  __syncthreads();

  // ---- addedge: u = h2 @ e_w1 -> Hc region; stage e_b1/e_w2 ----
  if (tid < HID) { gp[tid] = e_b1[tid]; zh[tid] = e_w2[tid]; }
  {
    bf16x8 af[4];
    #pragma unroll
    for (int ks = 0; ks < 4; ++ks)
      af[ks] = *(const bf16x8*)(Hr + (rb+cl)*136 + ks*32 + qd*8);
    #pragma unroll
    for (int ct = 0; ct < 8; ++ct) {
      f32x4 acc = {0.f, 0.f, 0.f, 0.f};
      #pragma unroll
      for (int ks = 0; ks < 4; ++ks) {
        const bf16x8 b = *(const bf16x8*)(g_ew1 + ((ct*4+ks)*64 + lane)*8);
        acc = __builtin_amdgcn_mfma_f32_16x16x32_bf16(af[ks], b, acc, 0, 0, 0);
      }
      const int n = ct*16 + cl;
      #pragma unroll
      for (int r = 0; r < 4; ++r)
        a1b[(rb + qd*4 + r)*136 + n] = f2bf(acc[r]);
    }
  }
  __syncthreads();

  // ---- addedge pairs ----
  {
    const int2 pr = *(const int2*)(nedg + 2*(gid*NEPG + tid));
    const ushort_t* ui = a1b + (pr.x - nb)*136;
    const ushort_t* uj = a1b + (pr.y - nb)*136;
    float ssum = 0.f;
    #pragma unroll
    for (int q8 = 0; q8 < 16; ++q8) {
      const bf16x8 va = *(const bf16x8*)(ui + q8*8);
      const bf16x8 vb = *(const bf16x8*)(uj + q8*8);
      #pragma unroll
      for (int j = 0; j < 8; ++j) {
        const int c = q8*8 + j;
        float v = bf2f((ushort_t)va[j]) + bf2f((ushort_t)vb[j]) + gp[c];
        v = fmaxf(v, 0.f);
        ssum = fmaf(v, zh[c], ssum);
      }
    }
    out[(size_t)gid*OUT_PG + 1 + NPG*NOUT + tid] = ssum + e_b2[0];
  }
}

// ---------------------------------------------------------------------------
extern "C" void kernel_launch(void* const* d_in, const int* in_sizes, int n_in,
                              void* d_out, int out_size, void* d_ws, size_t ws_size,
                              hipStream_t stream) {
  const float* node_tab = (const float*)d_in[0];
  const float* edge_tab = (const float*)d_in[1];
  const float* c1_w  = (const float*)d_in[2];
  const float* c1_we = (const float*)d_in[3];
  const float* c1_as = (const float*)d_in[4];
  const float* c1_ad = (const float*)d_in[5];
  const float* c1_ae = (const float*)d_in[6];
  const float* c1_b  = (const float*)d_in[7];
  const float* c2_w  = (const float*)d_in[8];
  const float* c2_we = (const float*)d_in[9];
  const float* c2_as = (const float*)d_in[10];
  const float* c2_ad = (const float*)d_in[11];
  const float* c2_ae = (const float*)d_in[12];
  const float* c2_b  = (const float*)d_in[13];
  const float* s_w1  = (const float*)d_in[14];
  const float* s_b1  = (const float*)d_in[15];
  const float* s_w2  = (const float*)d_in[16];
  const float* s_b2  = (const float*)d_in[17];
  const float* n_w1  = (const float*)d_in[18];
  const float* n_b1  = (const float*)d_in[19];
  const float* n_w2  = (const float*)d_in[20];
  const float* n_b2  = (const float*)d_in[21];
  const float* e_w1  = (const float*)d_in[22];
  const float* e_b1  = (const float*)d_in[23];
  const float* e_w2  = (const float*)d_in[24];
  const float* e_b2  = (const float*)d_in[25];
  const int* x    = (const int*)d_in[26];
  const int* ei   = (const int*)d_in[27];
  const int* ea   = (const int*)d_in[28];
  const int* nedg = (const int*)d_in[29];
  float* out = (float*)d_out;

  prep_kernel<<<dim3(57), dim3(256), 0, stream>>>(
      node_tab, edge_tab, c1_w, c1_we, c1_as, c1_ad, c1_ae,
      c2_w, c2_we, c2_ae, s_w1, n_w1, n_w2, e_w1);

  graph_kernel<<<dim3(B_GR), dim3(256), 0, stream>>>(
      c1_b, c2_as, c2_ad, c2_b, s_b1, s_w2, s_b2,
      n_b1, n_b2, e_b1, e_w2, e_b2, x, ei, ea, nedg, out);
}

// Round 6
// 205.761 us; speedup vs baseline: 3.3439x; 1.0754x over previous
//
#include <hip/hip_runtime.h>

// ---------------------------------------------------------------------------
// GNN action-value net, MI355X. Round 6: whole-grid co-residency.
//  * LDS 39.97KB -> 4 blocks/CU -> all 1024 blocks resident (no tail).
//  * Softmax: no max-subtraction (logits ~1e-2 by construction; shift-
//    invariant), P kept unnormalized in bf16, 1/den folded into agg epilogue.
//  * Layer-1 matmul emb@c1_w done in-block via MFMA (prep = weight packing
//    only, 7 blocks).
//  * In-place Pf(f32) -> P(bf16) conversion + A-frag preload barriers let
//    Hr overlay the P region.
// Fragment maps (verified r5): A[m][k]: m=lane&15, k=(lane>>4)*8+j;
// B[k][n]: n=lane&15, k=(lane>>4)*8+j; C/D: col=lane&15, row=(lane>>4)*4+reg.
// ---------------------------------------------------------------------------

#define NPG 64
#define EPG 1024
#define NEPG 256
#define B_GR 1024
#define E_TOT 1048576
#define EMB 64
#define HID 128
#define NOUT 101
#define OUT_PG 6721            // 1 + 64*101 + 256

typedef __attribute__((ext_vector_type(8))) short bf16x8;
typedef __attribute__((ext_vector_type(4))) float f32x4;
typedef unsigned short ushort_t;

__device__ ushort_t g_c1w[EMB*HID];      // frag-packed bf16 (K=64)
__device__ ushort_t g_c2w[HID*HID];      // frag-packed bf16
__device__ ushort_t g_nw1[HID*HID];
__device__ ushort_t g_ew1[HID*HID];
__device__ ushort_t g_nw2[HID*112];      // N padded 101 -> 112
__device__ float    g_sw1t[HID*HID];     // s_w1 transposed, f32
__device__ float    g_he1[4], g_he2[4];

__device__ __forceinline__ ushort_t f2bf(float f) {
  unsigned u = __float_as_uint(f);
  return (ushort_t)((u + 0x7fffu + ((u >> 16) & 1u)) >> 16);
}
__device__ __forceinline__ float bf2f(ushort_t h) {
  return __uint_as_float(((unsigned)h) << 16);
}

// ---------------------------------------------------------------------------
__global__ void prep_kernel(
    const float* __restrict__ edge_tab,
    const float* __restrict__ c1_w,  const float* __restrict__ c1_we,
    const float* __restrict__ c1_ae,
    const float* __restrict__ c2_w,  const float* __restrict__ c2_we,
    const float* __restrict__ c2_ae,
    const float* __restrict__ s_w1,  const float* __restrict__ n_w1,
    const float* __restrict__ n_w2,  const float* __restrict__ e_w1)
{
  const int b = blockIdx.x, tid = threadIdx.x;
  if (b == 0) {                       // per-edge-type logit constants
    __shared__ float v1[EMB], v2[EMB];
    if (tid < EMB) {
      float a = 0.f, d = 0.f;
      for (int j = 0; j < HID; ++j) {
        a = fmaf(c1_we[tid*HID + j], c1_ae[j], a);
        d = fmaf(c2_we[tid*HID + j], c2_ae[j], d);
      }
      v1[tid] = a; v2[tid] = d;
    }
    __syncthreads();
    if (tid < 4) {
      float a = 0.f, d = 0.f;
      for (int k = 0; k < EMB; ++k) {
        const float ev = edge_tab[tid*EMB + k];
        a = fmaf(ev, v1[k], a); d = fmaf(ev, v2[k], d);
      }
      g_he1[tid] = a; g_he2[tid] = d;
    }
  } else if (b == 1) {                // pack c1_w 64x128 (ks 0..1, ct 0..7)
    for (int idx = tid; idx < EMB*HID; idx += 256) {
      const int j = idx & 7, l = (idx >> 3) & 63, r2 = idx >> 9;
      const int ks = r2 & 1, ct = r2 >> 1;
      const int row = ks*32 + (l >> 4)*8 + j;
      const int col = ct*16 + (l & 15);
      g_c1w[idx] = f2bf(c1_w[row*HID + col]);
    }
  } else if (b >= 2 && b <= 4) {      // pack 128x128 weights
    const float* W = (b == 2) ? c2_w : (b == 3) ? n_w1 : e_w1;
    ushort_t* G = (b == 2) ? g_c2w : (b == 3) ? g_nw1 : g_ew1;
    for (int idx = tid; idx < HID*HID; idx += 256) {
      const int j = idx & 7, l = (idx >> 3) & 63, r2 = idx >> 9;
      const int ks = r2 & 3, ct = r2 >> 2;
      const int row = ks*32 + (l >> 4)*8 + j;
      const int col = ct*16 + (l & 15);
      G[idx] = f2bf(W[row*HID + col]);
    }
  } else if (b == 5) {                // pack n_w2 (128x101 -> 128x112)
    for (int idx = tid; idx < HID*112; idx += 256) {
      const int j = idx & 7, l = (idx >> 3) & 63, r2 = idx >> 9;
      const int ks = r2 & 3, ct = r2 >> 2;     // ct 0..6
      const int row = ks*32 + (l >> 4)*8 + j;
      const int col = ct*16 + (l & 15);
      g_nw2[idx] = (col < NOUT) ? f2bf(n_w2[row*NOUT + col]) : (ushort_t)0;
    }
  } else {                            // b == 6: s_w1 transpose (f32)
    for (int idx = tid; idx < HID*HID; idx += 256)
      g_sw1t[idx] = s_w1[(idx & 127)*HID + (idx >> 7)];
  }
}

// ---------------------------------------------------------------------------
// LDS map (bytes). Region R overlays Ae / Pf / P(bf16) / Hr.
#define S_HC  0        // 128x72 ushort col-major (feat,node); also 64x136 rows
#define S_R   18432    // max(Pf 16384, Hr 64x136x2=17408, Ae 64x72x2)
#define S_TP  35840    // topo ushort[1024] (2048B); later part f32[256]
#define S_DEN 37888    // 64 f32
#define S_NS  38144    // 64 f32
#define S_ND  38400    // 64 f32
#define S_XS  38656    // 64 int
#define S_GP  38912    // 128 f32 (pool; later e_b1)
#define S_ZH  39424    // 128 f32 (stop hidden; later e_w2)
#define S_HCC 39936    // 8 f32
#define S_TOT 39968

__global__ __launch_bounds__(256, 4) void graph_kernel(
    const float* __restrict__ node_tab,
    const float* __restrict__ c1_as, const float* __restrict__ c1_ad,
    const float* __restrict__ c1_b,
    const float* __restrict__ c2_as, const float* __restrict__ c2_ad,
    const float* __restrict__ c2_b,
    const float* __restrict__ s_b1,  const float* __restrict__ s_w2,
    const float* __restrict__ s_b2,
    const float* __restrict__ n_b1,  const float* __restrict__ n_b2,
    const float* __restrict__ e_b1,  const float* __restrict__ e_w2,
    const float* __restrict__ e_b2,
    const int* __restrict__ x,  const int* __restrict__ ei,
    const int* __restrict__ ea, const int* __restrict__ nedg,
    float* __restrict__ out)
{
  const int tid = threadIdx.x;
  const int gid = blockIdx.x;
  const int nb = gid * NPG;
  const int lane = tid & 63;
  const int wv = tid >> 6;
  const int qd = lane >> 4;        // quad (k-group / row-group)
  const int cl = lane & 15;        // col-in-tile / row-in-tile for A
  const int rb = wv * 16;          // this wave's M-tile base row

  __shared__ __align__(16) char smem[S_TOT];
  ushort_t* Hc   = (ushort_t*)(smem + S_HC);   // stride 72 (feat-major)
  ushort_t* Ae   = (ushort_t*)(smem + S_R);    // stride 72
  float*    Pf   = (float*)   (smem + S_R);    // 64x64 f32
  ushort_t* Pb   = (ushort_t*)(smem + S_R);    // stride 72 (in-place bf16)
  ushort_t* Hr   = (ushort_t*)(smem + S_R);    // stride 136
  ushort_t* topo = (ushort_t*)(smem + S_TP);
  float*    part = (float*)   (smem + S_TP);   // overlays topo (dead by then)
  float*    den  = (float*)   (smem + S_DEN);
  float*    ns   = (float*)   (smem + S_NS);
  float*    nd   = (float*)   (smem + S_ND);
  int*      xs   = (int*)     (smem + S_XS);
  float*    gp   = (float*)   (smem + S_GP);
  float*    zh   = (float*)   (smem + S_ZH);
  float*    hc   = (float*)   (smem + S_HCC);
  ushort_t* a1b  = Hc;                         // 64x136 rows (addnode/addedge)

  // ---- P0: topology + consts ----
  for (int k = tid; k < EPG; k += 256) {
    const int s = ei[gid*EPG + k] - nb;
    const int d = ei[E_TOT + gid*EPG + k] - nb;
    const int t = ea[gid*EPG + k];
    topo[k] = (ushort_t)(s | (d << 6) | (t << 12));
  }
  if (tid < NPG) xs[tid] = x[nb + tid];
  if (tid >= 64 && tid < 72) hc[tid-64] = (tid < 68) ? g_he1[tid-64] : g_he2[tid-68];
  if (tid >= 128) gp[tid-128] = 0.f;
  __syncthreads();

  // ---- P1: gather embeddings -> Ae (bf16 rows, stride 72) ----
  {
    const int n = tid >> 2;
    const int f0 = (tid & 3) * 16;
    const float* src = node_tab + xs[n]*EMB + f0;
    const float4 v0 = ((const float4*)src)[0];
    const float4 v1 = ((const float4*)src)[1];
    const float4 v2 = ((const float4*)src)[2];
    const float4 v3 = ((const float4*)src)[3];
    bf16x8 o0, o1;
    o0[0]=f2bf(v0.x); o0[1]=f2bf(v0.y); o0[2]=f2bf(v0.z); o0[3]=f2bf(v0.w);
    o0[4]=f2bf(v1.x); o0[5]=f2bf(v1.y); o0[6]=f2bf(v1.z); o0[7]=f2bf(v1.w);
    o1[0]=f2bf(v2.x); o1[1]=f2bf(v2.y); o1[2]=f2bf(v2.z); o1[3]=f2bf(v2.w);
    o1[4]=f2bf(v3.x); o1[5]=f2bf(v3.y); o1[6]=f2bf(v3.z); o1[7]=f2bf(v3.w);
    *(bf16x8*)(Ae + n*72 + f0)     = o0;
    *(bf16x8*)(Ae + n*72 + f0 + 8) = o1;
  }
  __syncthreads();

  // ---- P2: h1pre = emb @ c1_w (MFMA, K=64) -> Hc col-major + ns/nd ----
  {
    const bf16x8 af0 = *(const bf16x8*)(Ae + (rb+cl)*72 + qd*8);
    const bf16x8 af1 = *(const bf16x8*)(Ae + (rb+cl)*72 + 32 + qd*8);
    float pns[4] = {0.f,0.f,0.f,0.f}, pnd[4] = {0.f,0.f,0.f,0.f};
    #pragma unroll
    for (int ct = 0; ct < 8; ++ct) {
      f32x4 acc = {0.f, 0.f, 0.f, 0.f};
      const bf16x8 b0 = *(const bf16x8*)(g_c1w + ((ct*2+0)*64 + lane)*8);
      const bf16x8 b1 = *(const bf16x8*)(g_c1w + ((ct*2+1)*64 + lane)*8);
      acc = __builtin_amdgcn_mfma_f32_16x16x32_bf16(af0, b0, acc, 0, 0, 0);
      acc = __builtin_amdgcn_mfma_f32_16x16x32_bf16(af1, b1, acc, 0, 0, 0);
      const int n = ct*16 + cl;
      const float asv = c1_as[n], adv = c1_ad[n];
      #pragma unroll
      for (int r = 0; r < 4; ++r) {
        const float v = acc[r];
        Hc[n*72 + (rb + qd*4 + r)] = f2bf(v);
        pns[r] = fmaf(v, asv, pns[r]);
        pnd[r] = fmaf(v, adv, pnd[r]);
      }
    }
    #pragma unroll
    for (int r = 0; r < 4; ++r) {
      #pragma unroll
      for (int off = 1; off < 16; off <<= 1) {
        pns[r] += __shfl_xor(pns[r], off, 64);
        pnd[r] += __shfl_xor(pnd[r], off, 64);
      }
    }
    if (cl == 0) {
      #pragma unroll
      for (int r = 0; r < 4; ++r) { ns[rb+qd*4+r] = pns[r]; nd[rb+qd*4+r] = pnd[r]; }
    }
  }
  __syncthreads();

  // ---- P3: zero Pf + den (Ae dead) ----
  {
    float4* pz = (float4*)Pf;
    #pragma unroll
    for (int j = 0; j < 4; ++j) pz[tid + j*256] = make_float4(0.f,0.f,0.f,0.f);
    if (tid < NPG) den[tid] = 0.f;
  }
  __syncthreads();

  // ---- P4: layer-1 edge pass (no max-sub; logits ~1e-2) ----
  for (int k = tid; k < EPG; k += 256) {
    const int tp = topo[k];
    const int s = tp & 63, d = (tp >> 6) & 63, t = tp >> 12;
    float l = ns[s] + nd[d] + hc[t];
    l = (l > 0.f) ? l : 0.2f * l;
    const float ex = __expf(l);
    atomicAdd(&den[d], ex);
    atomicAdd(&Pf[d*64 + s], ex);
  }
  __syncthreads();

  // ---- P5: in-place Pf(f32) -> Pb(bf16, stride 72), unnormalized ----
  {
    float vreg[16];
    #pragma unroll
    for (int j = 0; j < 16; ++j) vreg[j] = Pf[tid + j*256];
    __syncthreads();
    #pragma unroll
    for (int j = 0; j < 16; ++j) {
      const int i = tid + j*256;
      Pb[(i >> 6)*72 + (i & 63)] = f2bf(vreg[j]);
    }
  }
  __syncthreads();

  // ---- P6: agg1 (MFMA): h1 = relu(inv*(P@h1pre) + c1_b) -> Hr ----
  {
    const bf16x8 a0 = *(const bf16x8*)(Pb + (rb+cl)*72 + qd*8);
    const bf16x8 a1 = *(const bf16x8*)(Pb + (rb+cl)*72 + 32 + qd*8);
    float inv4[4];
    #pragma unroll
    for (int r = 0; r < 4; ++r) inv4[r] = 1.f / (den[rb+qd*4+r] + 1e-16f);
    __syncthreads();                       // all A-frags read before Hr writes
    #pragma unroll
    for (int ct = 0; ct < 8; ++ct) {
      f32x4 acc = {0.f, 0.f, 0.f, 0.f};
      const bf16x8 b0 = *(const bf16x8*)(Hc + (ct*16+cl)*72 + qd*8);
      const bf16x8 b1 = *(const bf16x8*)(Hc + (ct*16+cl)*72 + 32 + qd*8);
      acc = __builtin_amdgcn_mfma_f32_16x16x32_bf16(a0, b0, acc, 0, 0, 0);
      acc = __builtin_amdgcn_mfma_f32_16x16x32_bf16(a1, b1, acc, 0, 0, 0);
      const int n = ct*16 + cl;
      const float bias = c1_b[n];
      #pragma unroll
      for (int r = 0; r < 4; ++r)
        Hr[(rb + qd*4 + r)*136 + n] = f2bf(fmaxf(fmaf(acc[r], inv4[r], bias), 0.f));
    }
  }
  __syncthreads();

  // ---- P7: h2pre = h1 @ c2_w (MFMA) -> Hc col-major + ns/nd ----
  {
    bf16x8 af[4];
    #pragma unroll
    for (int ks = 0; ks < 4; ++ks)
      af[ks] = *(const bf16x8*)(Hr + (rb+cl)*136 + ks*32 + qd*8);
    float pns[4] = {0.f,0.f,0.f,0.f}, pnd[4] = {0.f,0.f,0.f,0.f};
    #pragma unroll
    for (int ct = 0; ct < 8; ++ct) {
      f32x4 acc = {0.f, 0.f, 0.f, 0.f};
      #pragma unroll
      for (int ks = 0; ks < 4; ++ks) {
        const bf16x8 b = *(const bf16x8*)(g_c2w + ((ct*4+ks)*64 + lane)*8);
        acc = __builtin_amdgcn_mfma_f32_16x16x32_bf16(af[ks], b, acc, 0, 0, 0);
      }
      const int n = ct*16 + cl;
      const float asv = c2_as[n], adv = c2_ad[n];
      #pragma unroll
      for (int r = 0; r < 4; ++r) {
        const float v = acc[r];
        Hc[n*72 + (rb + qd*4 + r)] = f2bf(v);
        pns[r] = fmaf(v, asv, pns[r]);
        pnd[r] = fmaf(v, adv, pnd[r]);
      }
    }
    #pragma unroll
    for (int r = 0; r < 4; ++r) {
      #pragma unroll
      for (int off = 1; off < 16; off <<= 1) {
        pns[r] += __shfl_xor(pns[r], off, 64);
        pnd[r] += __shfl_xor(pnd[r], off, 64);
      }
    }
    if (cl == 0) {
      #pragma unroll
      for (int r = 0; r < 4; ++r) { ns[rb+qd*4+r] = pns[r]; nd[rb+qd*4+r] = pnd[r]; }
    }
  }
  __syncthreads();

  // ---- P8: zero Pf + den (h1 dead) ----
  {
    float4* pz = (float4*)Pf;
    #pragma unroll
    for (int j = 0; j < 4; ++j) pz[tid + j*256] = make_float4(0.f,0.f,0.f,0.f);
    if (tid < NPG) den[tid] = 0.f;
  }
  __syncthreads();

  // ---- P9: layer-2 edge pass ----
  for (int k = tid; k < EPG; k += 256) {
    const int tp = topo[k];
    const int s = tp & 63, d = (tp >> 6) & 63, t = tp >> 12;
    float l = ns[s] + nd[d] + hc[4 + t];
    l = (l > 0.f) ? l : 0.2f * l;
    const float ex = __expf(l);
    atomicAdd(&den[d], ex);
    atomicAdd(&Pf[d*64 + s], ex);
  }
  __syncthreads();

  // ---- P10: in-place conv ----
  {
    float vreg[16];
    #pragma unroll
    for (int j = 0; j < 16; ++j) vreg[j] = Pf[tid + j*256];
    __syncthreads();
    #pragma unroll
    for (int j = 0; j < 16; ++j) {
      const int i = tid + j*256;
      Pb[(i >> 6)*72 + (i & 63)] = f2bf(vreg[j]);
    }
  }
  __syncthreads();

  // ---- P11: agg2 (MFMA): h2 = inv*(P@h2pre) + c2_b -> Hr + pooling ----
  {
    const bf16x8 a0 = *(const bf16x8*)(Pb + (rb+cl)*72 + qd*8);
    const bf16x8 a1 = *(const bf16x8*)(Pb + (rb+cl)*72 + 32 + qd*8);
    float inv4[4];
    #pragma unroll
    for (int r = 0; r < 4; ++r) inv4[r] = 1.f / (den[rb+qd*4+r] + 1e-16f);
    __syncthreads();
    #pragma unroll
    for (int ct = 0; ct < 8; ++ct) {
      f32x4 acc = {0.f, 0.f, 0.f, 0.f};
      const bf16x8 b0 = *(const bf16x8*)(Hc + (ct*16+cl)*72 + qd*8);
      const bf16x8 b1 = *(const bf16x8*)(Hc + (ct*16+cl)*72 + 32 + qd*8);
      acc = __builtin_amdgcn_mfma_f32_16x16x32_bf16(a0, b0, acc, 0, 0, 0);
      acc = __builtin_amdgcn_mfma_f32_16x16x32_bf16(a1, b1, acc, 0, 0, 0);
      const int n = ct*16 + cl;
      const float bias = c2_b[n];
      float colsum = 0.f;
      #pragma unroll
      for (int r = 0; r < 4; ++r) {
        const float v = fmaf(acc[r], inv4[r], bias);
        Hr[(rb + qd*4 + r)*136 + n] = f2bf(v);
        colsum += v;
      }
      colsum += __shfl_xor(colsum, 16, 64);
      colsum += __shfl_xor(colsum, 32, 64);
      if (qd == 0) atomicAdd(&gp[n], colsum);
    }
  }
  __syncthreads();

  // ---- P12: stop head (part overlays topo; topo dead) ----
  {
    const int j = tid & 127, half = tid >> 7;
    const float* wr = g_sw1t + j*HID + half*64;
    const float* gr = gp + half*64;
    float p = 0.f;
    #pragma unroll
    for (int q = 0; q < 16; ++q) {
      const float4 w = ((const float4*)wr)[q];
      const float4 g = ((const float4*)gr)[q];
      p = fmaf(w.x, g.x, p); p = fmaf(w.y, g.y, p);
      p = fmaf(w.z, g.z, p); p = fmaf(w.w, g.w, p);
    }
    part[tid] = p;
  }
  __syncthreads();
  if (tid < HID) zh[tid] = fmaxf(part[tid] + part[tid+128] + s_b1[tid], 0.f);
  __syncthreads();
  if (tid < 64) {
    float p = fmaf(zh[tid], s_w2[tid], zh[tid+64]*s_w2[tid+64]);
    #pragma unroll
    for (int off = 32; off > 0; off >>= 1) p += __shfl_down(p, off, 64);
    if (tid == 0) out[(size_t)gid*OUT_PG] = p + s_b2[0];
  }
  __syncthreads();

  // ---- P13: addnode a1 = relu(h2 @ n_w1 + n_b1) -> a1b (Hc region) ----
  {
    bf16x8 af[4];
    #pragma unroll
    for (int ks = 0; ks < 4; ++ks)
      af[ks] = *(const bf16x8*)(Hr + (rb+cl)*136 + ks*32 + qd*8);
    #pragma unroll
    for (int ct = 0; ct < 8; ++ct) {
      f32x4 acc = {0.f, 0.f, 0.f, 0.f};
      #pragma unroll
      for (int ks = 0; ks < 4; ++ks) {
        const bf16x8 b = *(const bf16x8*)(g_nw1 + ((ct*4+ks)*64 + lane)*8);
        acc = __builtin_amdgcn_mfma_f32_16x16x32_bf16(af[ks], b, acc, 0, 0, 0);
      }
      const int n = ct*16 + cl;
      const float bias = n_b1[n];
      #pragma unroll
      for (int r = 0; r < 4; ++r)
        a1b[(rb + qd*4 + r)*136 + n] = f2bf(fmaxf(acc[r] + bias, 0.f));
    }
  }
  __syncthreads();

  // ---- P14: addnode out = a1 @ n_w2p + n_b2 ----
  {
    bf16x8 af[4];
    #pragma unroll
    for (int ks = 0; ks < 4; ++ks)
      af[ks] = *(const bf16x8*)(a1b + (rb+cl)*136 + ks*32 + qd*8);
    float* ob = out + (size_t)gid*OUT_PG + 1;
    #pragma unroll
    for (int ct = 0; ct < 7; ++ct) {
      f32x4 acc = {0.f, 0.f, 0.f, 0.f};
      #pragma unroll
      for (int ks = 0; ks < 4; ++ks) {
        const bf16x8 b = *(const bf16x8*)(g_nw2 + ((ct*4+ks)*64 + lane)*8);
        acc = __builtin_amdgcn_mfma_f32_16x16x32_bf16(af[ks], b, acc, 0, 0, 0);
      }
      const int o = ct*16 + cl;
      if (o < NOUT) {
        const float b2 = n_b2[o];
        #pragma unroll
        for (int r = 0; r < 4; ++r)
          ob[(size_t)(rb + qd*4 + r)*NOUT + o] = acc[r] + b2;
      }
    }
  }
  __syncthreads();

  // ---- P15: addedge u = h2 @ e_w1 -> a1b; stage e_b1/e_w2 ----
  if (tid < HID) { gp[tid] = e_b1[tid]; zh[tid] = e_w2[tid]; }
  {
    bf16x8 af[4];
    #pragma unroll
    for (int ks = 0; ks < 4; ++ks)
      af[ks] = *(const bf16x8*)(Hr + (rb+cl)*136 + ks*32 + qd*8);
    #pragma unroll
    for (int ct = 0; ct < 8; ++ct) {
      f32x4 acc = {0.f, 0.f, 0.f, 0.f};
      #pragma unroll
      for (int ks = 0; ks < 4; ++ks) {
        const bf16x8 b = *(const bf16x8*)(g_ew1 + ((ct*4+ks)*64 + lane)*8);
        acc = __builtin_amdgcn_mfma_f32_16x16x32_bf16(af[ks], b, acc, 0, 0, 0);
      }
      const int n = ct*16 + cl;
      #pragma unroll
      for (int r = 0; r < 4; ++r)
        a1b[(rb + qd*4 + r)*136 + n] = f2bf(acc[r]);
    }
  }
  __syncthreads();

  // ---- P16: addedge pairs ----
  {
    const int2 pr = *(const int2*)(nedg + 2*(gid*NEPG + tid));
    const ushort_t* ui = a1b + (pr.x - nb)*136;
    const ushort_t* uj = a1b + (pr.y - nb)*136;
    float ssum = 0.f;
    #pragma unroll
    for (int q8 = 0; q8 < 16; ++q8) {
      const bf16x8 va = *(const bf16x8*)(ui + q8*8);
      const bf16x8 vb = *(const bf16x8*)(uj + q8*8);
      #pragma unroll
      for (int j = 0; j < 8; ++j) {
        const int c = q8*8 + j;
        float v = bf2f((ushort_t)va[j]) + bf2f((ushort_t)vb[j]) + gp[c];
        v = fmaxf(v, 0.f);
        ssum = fmaf(v, zh[c], ssum);
      }
    }
    out[(size_t)gid*OUT_PG + 1 + NPG*NOUT + tid] = ssum + e_b2[0];
  }
}

// ---------------------------------------------------------------------------
extern "C" void kernel_launch(void* const* d_in, const int* in_sizes, int n_in,
                              void* d_out, int out_size, void* d_ws, size_t ws_size,
                              hipStream_t stream) {
  const float* node_tab = (const float*)d_in[0];
  const float* edge_tab = (const float*)d_in[1];
  const float* c1_w  = (const float*)d_in[2];
  const float* c1_we = (const float*)d_in[3];
  const float* c1_as = (const float*)d_in[4];
  const float* c1_ad = (const float*)d_in[5];
  const float* c1_ae = (const float*)d_in[6];
  const float* c1_b  = (const float*)d_in[7];
  const float* c2_w  = (const float*)d_in[8];
  const float* c2_we = (const float*)d_in[9];
  const float* c2_as = (const float*)d_in[10];
  const float* c2_ad = (const float*)d_in[11];
  const float* c2_ae = (const float*)d_in[12];
  const float* c2_b  = (const float*)d_in[13];
  const float* s_w1  = (const float*)d_in[14];
  const float* s_b1  = (const float*)d_in[15];
  const float* s_w2  = (const float*)d_in[16];
  const float* s_b2  = (const float*)d_in[17];
  const float* n_w1  = (const float*)d_in[18];
  const float* n_b1  = (const float*)d_in[19];
  const float* n_w2  = (const float*)d_in[20];
  const float* n_b2  = (const float*)d_in[21];
  const float* e_w1  = (const float*)d_in[22];
  const float* e_b1  = (const float*)d_in[23];
  const float* e_w2  = (const float*)d_in[24];
  const float* e_b2  = (const float*)d_in[25];
  const int* x    = (const int*)d_in[26];
  const int* ei   = (const int*)d_in[27];
  const int* ea   = (const int*)d_in[28];
  const int* nedg = (const int*)d_in[29];
  float* out = (float*)d_out;

  prep_kernel<<<dim3(7), dim3(256), 0, stream>>>(
      edge_tab, c1_w, c1_we, c1_ae, c2_w, c2_we, c2_ae,
      s_w1, n_w1, n_w2, e_w1);

  graph_kernel<<<dim3(B_GR), dim3(256), 0, stream>>>(
      node_tab, c1_as, c1_ad, c1_b, c2_as, c2_ad, c2_b,
      s_b1, s_w2, s_b2, n_b1, n_b2, e_b1, e_w2, e_b2,
      x, ei, ea, nedg, out);
}

// Round 7
// 201.610 us; speedup vs baseline: 3.4128x; 1.0206x over previous
//
#include <hip/hip_runtime.h>

// ---------------------------------------------------------------------------
// GNN action-value net, MI355X. Round 7: critical-path reduction.
// 11 barriers (was ~18). Wave-local row ownership exploited everywhere:
//  * emb A-frags loaded straight from global (no Ae staging phase)
//  * P(f32) -> bf16 fragment conversion done in-register at preload
//  * softmax denominator = row-sum of preloaded P frags (no den atomics)
//  * edge topology kept in 4 packed regs across both edge passes
//  * P13/P14/P15 (addnode/addedge staging) barrier-free (wave-local rows)
// LDS ~38.4KB -> 4 blocks/CU (grid = exactly 4 blocks/CU).
// Fragment maps (verified r5/r6): A[m][k]: m=lane&15, k=(lane>>4)*8+j;
// B[k][n]: n=lane&15, k=(lane>>4)*8+j; C/D: col=lane&15, row=(lane>>4)*4+reg.
// ---------------------------------------------------------------------------

#define NPG 64
#define EPG 1024
#define NEPG 256
#define B_GR 1024
#define E_TOT 1048576
#define EMB 64
#define HID 128
#define NOUT 101
#define OUT_PG 6721            // 1 + 64*101 + 256

typedef __attribute__((ext_vector_type(8))) short bf16x8;
typedef __attribute__((ext_vector_type(4))) float f32x4;
typedef unsigned short ushort_t;

__device__ ushort_t g_c1w[EMB*HID];      // frag-packed bf16 (K=64)
__device__ ushort_t g_c2w[HID*HID];      // frag-packed bf16
__device__ ushort_t g_nw1[HID*HID];
__device__ ushort_t g_ew1[HID*HID];
__device__ ushort_t g_nw2[HID*112];      // N padded 101 -> 112
__device__ float    g_sw1t[HID*HID];     // s_w1 transposed, f32
__device__ float    g_he1[4], g_he2[4];

__device__ __forceinline__ ushort_t f2bf(float f) {
  unsigned u = __float_as_uint(f);
  return (ushort_t)((u + 0x7fffu + ((u >> 16) & 1u)) >> 16);
}
__device__ __forceinline__ float bf2f(ushort_t h) {
  return __uint_as_float(((unsigned)h) << 16);
}

// ---------------------------------------------------------------------------
__global__ void prep_kernel(
    const float* __restrict__ edge_tab,
    const float* __restrict__ c1_w,  const float* __restrict__ c1_we,
    const float* __restrict__ c1_ae,
    const float* __restrict__ c2_w,  const float* __restrict__ c2_we,
    const float* __restrict__ c2_ae,
    const float* __restrict__ s_w1,  const float* __restrict__ n_w1,
    const float* __restrict__ n_w2,  const float* __restrict__ e_w1)
{
  const int b = blockIdx.x, tid = threadIdx.x;
  if (b == 0) {                       // per-edge-type logit constants
    __shared__ float v1[EMB], v2[EMB];
    if (tid < EMB) {
      float a = 0.f, d = 0.f;
      for (int j = 0; j < HID; ++j) {
        a = fmaf(c1_we[tid*HID + j], c1_ae[j], a);
        d = fmaf(c2_we[tid*HID + j], c2_ae[j], d);
      }
      v1[tid] = a; v2[tid] = d;
    }
    __syncthreads();
    if (tid < 4) {
      float a = 0.f, d = 0.f;
      for (int k = 0; k < EMB; ++k) {
        const float ev = edge_tab[tid*EMB + k];
        a = fmaf(ev, v1[k], a); d = fmaf(ev, v2[k], d);
      }
      g_he1[tid] = a; g_he2[tid] = d;
    }
  } else if (b == 1) {                // pack c1_w 64x128 (ks 0..1, ct 0..7)
    for (int idx = tid; idx < EMB*HID; idx += 256) {
      const int j = idx & 7, l = (idx >> 3) & 63, r2 = idx >> 9;
      const int ks = r2 & 1, ct = r2 >> 1;
      const int row = ks*32 + (l >> 4)*8 + j;
      const int col = ct*16 + (l & 15);
      g_c1w[idx] = f2bf(c1_w[row*HID + col]);
    }
  } else if (b >= 2 && b <= 4) {      // pack 128x128 weights
    const float* W = (b == 2) ? c2_w : (b == 3) ? n_w1 : e_w1;
    ushort_t* G = (b == 2) ? g_c2w : (b == 3) ? g_nw1 : g_ew1;
    for (int idx = tid; idx < HID*HID; idx += 256) {
      const int j = idx & 7, l = (idx >> 3) & 63, r2 = idx >> 9;
      const int ks = r2 & 3, ct = r2 >> 2;
      const int row = ks*32 + (l >> 4)*8 + j;
      const int col = ct*16 + (l & 15);
      G[idx] = f2bf(W[row*HID + col]);
    }
  } else if (b == 5) {                // pack n_w2 (128x101 -> 128x112)
    for (int idx = tid; idx < HID*112; idx += 256) {
      const int j = idx & 7, l = (idx >> 3) & 63, r2 = idx >> 9;
      const int ks = r2 & 3, ct = r2 >> 2;     // ct 0..6
      const int row = ks*32 + (l >> 4)*8 + j;
      const int col = ct*16 + (l & 15);
      g_nw2[idx] = (col < NOUT) ? f2bf(n_w2[row*NOUT + col]) : (ushort_t)0;
    }
  } else {                            // b == 6: s_w1 transpose (f32)
    for (int idx = tid; idx < HID*HID; idx += 256)
      g_sw1t[idx] = s_w1[(idx & 127)*HID + (idx >> 7)];
  }
}

// ---------------------------------------------------------------------------
// LDS map (bytes). Region R overlays Pf(64x64 f32) / Hr(64x136 ushort).
#define S_HC   0        // 128x72 ushort col-major; reused as a1b 64x136 rows
#define S_R    18432    // max(16384, 17408)
#define S_PART 35840    // 256 f32 (stop partials; later e_b1|e_w2)
#define S_NS   36864    // 64 f32
#define S_ND   37120    // 64 f32
#define S_GP   37376    // 128 f32 (pool)
#define S_ZH   37888    // 128 f32 (stop hidden)
#define S_HCC  38400    // 8 f32
#define S_TOT  38432

__global__ __launch_bounds__(256, 4) void graph_kernel(
    const float* __restrict__ node_tab,
    const float* __restrict__ c1_as, const float* __restrict__ c1_ad,
    const float* __restrict__ c1_b,
    const float* __restrict__ c2_as, const float* __restrict__ c2_ad,
    const float* __restrict__ c2_b,
    const float* __restrict__ s_b1,  const float* __restrict__ s_w2,
    const float* __restrict__ s_b2,
    const float* __restrict__ n_b1,  const float* __restrict__ n_b2,
    const float* __restrict__ e_b1,  const float* __restrict__ e_w2,
    const float* __restrict__ e_b2,
    const int* __restrict__ x,  const int* __restrict__ ei,
    const int* __restrict__ ea, const int* __restrict__ nedg,
    float* __restrict__ out)
{
  const int tid = threadIdx.x;
  const int gid = blockIdx.x;
  const int nb = gid * NPG;
  const int lane = tid & 63;
  const int wv = tid >> 6;
  const int qd = lane >> 4;        // quad
  const int cl = lane & 15;        // col/row-in-tile
  const int rb = wv * 16;          // wave's M-tile base row

  __shared__ __align__(16) char smem[S_TOT];
  ushort_t* Hc   = (ushort_t*)(smem + S_HC);   // stride 72 (feat-major)
  float*    Pf   = (float*)   (smem + S_R);    // 64x64 f32
  ushort_t* Hr   = (ushort_t*)(smem + S_R);    // stride 136 (row-major)
  float*    part = (float*)   (smem + S_PART);
  float*    ns   = (float*)   (smem + S_NS);
  float*    nd   = (float*)   (smem + S_ND);
  float*    gp   = (float*)   (smem + S_GP);
  float*    zh   = (float*)   (smem + S_ZH);
  float*    hc   = (float*)   (smem + S_HCC);
  ushort_t* a1b  = Hc;                         // 64x136 rows

  // ---- P0: edge regs, emb frags from global, zero Pf/gp, consts ----
  unsigned er[4];
  #pragma unroll
  for (int i = 0; i < 4; ++i) {
    const int k = tid + 256*i;
    const int s = ei[gid*EPG + k] - nb;
    const int d = ei[E_TOT + gid*EPG + k] - nb;
    const int t = ea[gid*EPG + k];
    er[i] = (unsigned)(s | (d << 6) | (t << 12));
  }
  bf16x8 ea0, ea1;                 // emb A-frags for row rb+cl
  {
    const int cat = x[nb + rb + cl];
    const float* src = node_tab + cat*EMB;
    const float4 v0 = *(const float4*)(src + qd*8);
    const float4 v1 = *(const float4*)(src + qd*8 + 4);
    const float4 v2 = *(const float4*)(src + 32 + qd*8);
    const float4 v3 = *(const float4*)(src + 36 + qd*8);
    ea0[0]=f2bf(v0.x); ea0[1]=f2bf(v0.y); ea0[2]=f2bf(v0.z); ea0[3]=f2bf(v0.w);
    ea0[4]=f2bf(v1.x); ea0[5]=f2bf(v1.y); ea0[6]=f2bf(v1.z); ea0[7]=f2bf(v1.w);
    ea1[0]=f2bf(v2.x); ea1[1]=f2bf(v2.y); ea1[2]=f2bf(v2.z); ea1[3]=f2bf(v2.w);
    ea1[4]=f2bf(v3.x); ea1[5]=f2bf(v3.y); ea1[6]=f2bf(v3.z); ea1[7]=f2bf(v3.w);
  }
  {
    float4* pz = (float4*)Pf;
    #pragma unroll
    for (int j = 0; j < 4; ++j) pz[tid + j*256] = make_float4(0.f,0.f,0.f,0.f);
  }
  if (tid < 128) gp[tid] = 0.f;
  if (tid < 8) hc[tid] = (tid < 4) ? g_he1[tid] : g_he2[tid-4];

  // ---- P2: h1pre = emb @ c1_w (MFMA) -> Hc col-major + ns/nd ----
  {
    float pns[4] = {0.f,0.f,0.f,0.f}, pnd[4] = {0.f,0.f,0.f,0.f};
    #pragma unroll
    for (int ct = 0; ct < 8; ++ct) {
      f32x4 acc = {0.f, 0.f, 0.f, 0.f};
      const bf16x8 b0 = *(const bf16x8*)(g_c1w + ((ct*2+0)*64 + lane)*8);
      const bf16x8 b1 = *(const bf16x8*)(g_c1w + ((ct*2+1)*64 + lane)*8);
      acc = __builtin_amdgcn_mfma_f32_16x16x32_bf16(ea0, b0, acc, 0, 0, 0);
      acc = __builtin_amdgcn_mfma_f32_16x16x32_bf16(ea1, b1, acc, 0, 0, 0);
      const int n = ct*16 + cl;
      const float asv = c1_as[n], adv = c1_ad[n];
      #pragma unroll
      for (int r = 0; r < 4; ++r) {
        const float v = acc[r];
        Hc[n*72 + (rb + qd*4 + r)] = f2bf(v);
        pns[r] = fmaf(v, asv, pns[r]);
        pnd[r] = fmaf(v, adv, pnd[r]);
      }
    }
    #pragma unroll
    for (int r = 0; r < 4; ++r) {
      #pragma unroll
      for (int off = 1; off < 16; off <<= 1) {
        pns[r] += __shfl_xor(pns[r], off, 64);
        pnd[r] += __shfl_xor(pnd[r], off, 64);
      }
    }
    if (cl == 0) {
      #pragma unroll
      for (int r = 0; r < 4; ++r) { ns[rb+qd*4+r] = pns[r]; nd[rb+qd*4+r] = pnd[r]; }
    }
  }
  __syncthreads();                                        // B2

  // ---- edge pass 1 (atomicAdd exp into Pf; no max-sub, no den) ----
  #pragma unroll
  for (int i = 0; i < 4; ++i) {
    const unsigned tp = er[i];
    const int s = tp & 63, d = (tp >> 6) & 63, t = tp >> 12;
    float l = ns[s] + nd[d] + hc[t];
    l = (l > 0.f) ? l : 0.2f * l;
    atomicAdd(&Pf[d*64 + s], __expf(l));
  }
  __syncthreads();                                        // B3

  // ---- agg1: preload P frags (f32->bf16 in-reg) + den rowsum ----
  bf16x8 pa0, pa1;
  float inv4[4];
  {
    const float* pr = Pf + (rb + cl)*64;
    const float4 v0 = *(const float4*)(pr + qd*8);
    const float4 v1 = *(const float4*)(pr + qd*8 + 4);
    const float4 v2 = *(const float4*)(pr + 32 + qd*8);
    const float4 v3 = *(const float4*)(pr + 36 + qd*8);
    pa0[0]=f2bf(v0.x); pa0[1]=f2bf(v0.y); pa0[2]=f2bf(v0.z); pa0[3]=f2bf(v0.w);
    pa0[4]=f2bf(v1.x); pa0[5]=f2bf(v1.y); pa0[6]=f2bf(v1.z); pa0[7]=f2bf(v1.w);
    pa1[0]=f2bf(v2.x); pa1[1]=f2bf(v2.y); pa1[2]=f2bf(v2.z); pa1[3]=f2bf(v2.w);
    pa1[4]=f2bf(v3.x); pa1[5]=f2bf(v3.y); pa1[6]=f2bf(v3.z); pa1[7]=f2bf(v3.w);
    float den = v0.x+v0.y+v0.z+v0.w + v1.x+v1.y+v1.z+v1.w
              + v2.x+v2.y+v2.z+v2.w + v3.x+v3.y+v3.z+v3.w;
    den += __shfl_xor(den, 16, 64);
    den += __shfl_xor(den, 32, 64);
    #pragma unroll
    for (int r = 0; r < 4; ++r)
      inv4[r] = 1.f / (__shfl(den, qd*4 + r, 64) + 1e-16f);
  }
  __syncthreads();                                        // B4 (Pf reads done)

  // ---- agg1 body: h1 = relu(inv*(P@h1pre) + c1_b) -> Hr ----
  {
    #pragma unroll
    for (int ct = 0; ct < 8; ++ct) {
      f32x4 acc = {0.f, 0.f, 0.f, 0.f};
      const bf16x8 b0 = *(const bf16x8*)(Hc + (ct*16+cl)*72 + qd*8);
      const bf16x8 b1 = *(const bf16x8*)(Hc + (ct*16+cl)*72 + 32 + qd*8);
      acc = __builtin_amdgcn_mfma_f32_16x16x32_bf16(pa0, b0, acc, 0, 0, 0);
      acc = __builtin_amdgcn_mfma_f32_16x16x32_bf16(pa1, b1, acc, 0, 0, 0);
      const int n = ct*16 + cl;
      const float bias = c1_b[n];
      #pragma unroll
      for (int r = 0; r < 4; ++r)
        Hr[(rb + qd*4 + r)*136 + n] = f2bf(fmaxf(fmaf(acc[r], inv4[r], bias), 0.f));
    }
  }
  // ---- P7 preload: h1 A-frags (wave-local rows, no barrier) ----
  bf16x8 h1f[4];
  #pragma unroll
  for (int ks = 0; ks < 4; ++ks)
    h1f[ks] = *(const bf16x8*)(Hr + (rb+cl)*136 + ks*32 + qd*8);
  __syncthreads();                                        // B5 (Hc h1pre reads done)

  // ---- P7 body: h2pre = h1 @ c2_w -> Hc + ns/nd; zero Pf ----
  {
    float4* pz = (float4*)Pf;
    #pragma unroll
    for (int j = 0; j < 4; ++j) pz[tid + j*256] = make_float4(0.f,0.f,0.f,0.f);
    float pns[4] = {0.f,0.f,0.f,0.f}, pnd[4] = {0.f,0.f,0.f,0.f};
    #pragma unroll
    for (int ct = 0; ct < 8; ++ct) {
      f32x4 acc = {0.f, 0.f, 0.f, 0.f};
      #pragma unroll
      for (int ks = 0; ks < 4; ++ks) {
        const bf16x8 b = *(const bf16x8*)(g_c2w + ((ct*4+ks)*64 + lane)*8);
        acc = __builtin_amdgcn_mfma_f32_16x16x32_bf16(h1f[ks], b, acc, 0, 0, 0);
      }
      const int n = ct*16 + cl;
      const float asv = c2_as[n], adv = c2_ad[n];
      #pragma unroll
      for (int r = 0; r < 4; ++r) {
        const float v = acc[r];
        Hc[n*72 + (rb + qd*4 + r)] = f2bf(v);
        pns[r] = fmaf(v, asv, pns[r]);
        pnd[r] = fmaf(v, adv, pnd[r]);
      }
    }
    #pragma unroll
    for (int r = 0; r < 4; ++r) {
      #pragma unroll
      for (int off = 1; off < 16; off <<= 1) {
        pns[r] += __shfl_xor(pns[r], off, 64);
        pnd[r] += __shfl_xor(pnd[r], off, 64);
      }
    }
    if (cl == 0) {
      #pragma unroll
      for (int r = 0; r < 4; ++r) { ns[rb+qd*4+r] = pns[r]; nd[rb+qd*4+r] = pnd[r]; }
    }
  }
  __syncthreads();                                        // B6

  // ---- edge pass 2 ----
  #pragma unroll
  for (int i = 0; i < 4; ++i) {
    const unsigned tp = er[i];
    const int s = tp & 63, d = (tp >> 6) & 63, t = tp >> 12;
    float l = ns[s] + nd[d] + hc[4 + t];
    l = (l > 0.f) ? l : 0.2f * l;
    atomicAdd(&Pf[d*64 + s], __expf(l));
  }
  __syncthreads();                                        // B7

  // ---- agg2 preload ----
  {
    const float* pr = Pf + (rb + cl)*64;
    const float4 v0 = *(const float4*)(pr + qd*8);
    const float4 v1 = *(const float4*)(pr + qd*8 + 4);
    const float4 v2 = *(const float4*)(pr + 32 + qd*8);
    const float4 v3 = *(const float4*)(pr + 36 + qd*8);
    pa0[0]=f2bf(v0.x); pa0[1]=f2bf(v0.y); pa0[2]=f2bf(v0.z); pa0[3]=f2bf(v0.w);
    pa0[4]=f2bf(v1.x); pa0[5]=f2bf(v1.y); pa0[6]=f2bf(v1.z); pa0[7]=f2bf(v1.w);
    pa1[0]=f2bf(v2.x); pa1[1]=f2bf(v2.y); pa1[2]=f2bf(v2.z); pa1[3]=f2bf(v2.w);
    pa1[4]=f2bf(v3.x); pa1[5]=f2bf(v3.y); pa1[6]=f2bf(v3.z); pa1[7]=f2bf(v3.w);
    float den = v0.x+v0.y+v0.z+v0.w + v1.x+v1.y+v1.z+v1.w
              + v2.x+v2.y+v2.z+v2.w + v3.x+v3.y+v3.z+v3.w;
    den += __shfl_xor(den, 16, 64);
    den += __shfl_xor(den, 32, 64);
    #pragma unroll
    for (int r = 0; r < 4; ++r)
      inv4[r] = 1.f / (__shfl(den, qd*4 + r, 64) + 1e-16f);
  }
  __syncthreads();                                        // B8

  // ---- agg2 body: h2 = inv*(P@h2pre) + c2_b -> Hr + pooling ----
  {
    #pragma unroll
    for (int ct = 0; ct < 8; ++ct) {
      f32x4 acc = {0.f, 0.f, 0.f, 0.f};
      const bf16x8 b0 = *(const bf16x8*)(Hc + (ct*16+cl)*72 + qd*8);
      const bf16x8 b1 = *(const bf16x8*)(Hc + (ct*16+cl)*72 + 32 + qd*8);
      acc = __builtin_amdgcn_mfma_f32_16x16x32_bf16(pa0, b0, acc, 0, 0, 0);
      acc = __builtin_amdgcn_mfma_f32_16x16x32_bf16(pa1, b1, acc, 0, 0, 0);
      const int n = ct*16 + cl;
      const float bias = c2_b[n];
      float colsum = 0.f;
      #pragma unroll
      for (int r = 0; r < 4; ++r) {
        const float v = fmaf(acc[r], inv4[r], bias);
        Hr[(rb + qd*4 + r)*136 + n] = f2bf(v);
        colsum += v;
      }
      colsum += __shfl_xor(colsum, 16, 64);
      colsum += __shfl_xor(colsum, 32, 64);
      if (qd == 0) atomicAdd(&gp[n], colsum);
    }
  }
  __syncthreads();                                        // B9

  // ---- stop head: partials ----
  {
    const int j = tid & 127, half = tid >> 7;
    const float* wr = g_sw1t + j*HID + half*64;
    const float* gr = gp + half*64;
    float p = 0.f;
    #pragma unroll
    for (int q = 0; q < 16; ++q) {
      const float4 w = ((const float4*)wr)[q];
      const float4 g = ((const float4*)gr)[q];
      p = fmaf(w.x, g.x, p); p = fmaf(w.y, g.y, p);
      p = fmaf(w.z, g.z, p); p = fmaf(w.w, g.w, p);
    }
    part[tid] = p;
  }
  __syncthreads();                                        // B10
  if (tid < HID) zh[tid] = fmaxf(part[tid] + part[tid+128] + s_b1[tid], 0.f);
  __syncthreads();                                        // B11

  // ---- post-B11: stop reduce (wave 0 lanes), stage e_b1/e_w2 into part,
  //      addnode (P13+P14) and addedge staging (P15), all barrier-free ----
  if (tid < 64) {
    float p = fmaf(zh[tid], s_w2[tid], zh[tid+64]*s_w2[tid+64]);
    #pragma unroll
    for (int off = 32; off > 0; off >>= 1) p += __shfl_down(p, off, 64);
    if (tid == 0) out[(size_t)gid*OUT_PG] = p + s_b2[0];
  }
  part[tid] = (tid < 128) ? e_b1[tid] : e_w2[tid-128];

  bf16x8 h2f[4];
  #pragma unroll
  for (int ks = 0; ks < 4; ++ks)
    h2f[ks] = *(const bf16x8*)(Hr + (rb+cl)*136 + ks*32 + qd*8);

  // P13: a1 = relu(h2 @ n_w1 + n_b1) -> a1b (wave-local rows)
  {
    #pragma unroll
    for (int ct = 0; ct < 8; ++ct) {
      f32x4 acc = {0.f, 0.f, 0.f, 0.f};
      #pragma unroll
      for (int ks = 0; ks < 4; ++ks) {
        const bf16x8 b = *(const bf16x8*)(g_nw1 + ((ct*4+ks)*64 + lane)*8);
        acc = __builtin_amdgcn_mfma_f32_16x16x32_bf16(h2f[ks], b, acc, 0, 0, 0);
      }
      const int n = ct*16 + cl;
      const float bias = n_b1[n];
      #pragma unroll
      for (int r = 0; r < 4; ++r)
        a1b[(rb + qd*4 + r)*136 + n] = f2bf(fmaxf(acc[r] + bias, 0.f));
    }
  }
  // P14: addnode out = a1 @ n_w2p + n_b2 (reads own wave's a1b rows)
  {
    bf16x8 af[4];
    #pragma unroll
    for (int ks = 0; ks < 4; ++ks)
      af[ks] = *(const bf16x8*)(a1b + (rb+cl)*136 + ks*32 + qd*8);
    float* ob = out + (size_t)gid*OUT_PG + 1;
    #pragma unroll
    for (int ct = 0; ct < 7; ++ct) {
      f32x4 acc = {0.f, 0.f, 0.f, 0.f};
      #pragma unroll
      for (int ks = 0; ks < 4; ++ks) {
        const bf16x8 b = *(const bf16x8*)(g_nw2 + ((ct*4+ks)*64 + lane)*8);
        acc = __builtin_amdgcn_mfma_f32_16x16x32_bf16(af[ks], b, acc, 0, 0, 0);
      }
      const int o = ct*16 + cl;
      if (o < NOUT) {
        const float b2 = n_b2[o];
        #pragma unroll
        for (int r = 0; r < 4; ++r)
          ob[(size_t)(rb + qd*4 + r)*NOUT + o] = acc[r] + b2;
      }
    }
  }
  // P15: u = h2 @ e_w1 -> a1b (own rows, after own P14 reads; in-wave order)
  {
    #pragma unroll
    for (int ct = 0; ct < 8; ++ct) {
      f32x4 acc = {0.f, 0.f, 0.f, 0.f};
      #pragma unroll
      for (int ks = 0; ks < 4; ++ks) {
        const bf16x8 b = *(const bf16x8*)(g_ew1 + ((ct*4+ks)*64 + lane)*8);
        acc = __builtin_amdgcn_mfma_f32_16x16x32_bf16(h2f[ks], b, acc, 0, 0, 0);
      }
      const int n = ct*16 + cl;
      #pragma unroll
      for (int r = 0; r < 4; ++r)
        a1b[(rb + qd*4 + r)*136 + n] = f2bf(acc[r]);
    }
  }
  __syncthreads();                                        // B12

  // ---- P16: addedge pairs ----
  {
    const int2 pr = *(const int2*)(nedg + 2*(gid*NEPG + tid));
    const ushort_t* ui = a1b + (pr.x - nb)*136;
    const ushort_t* uj = a1b + (pr.y - nb)*136;
    float ssum = 0.f;
    #pragma unroll
    for (int q8 = 0; q8 < 16; ++q8) {
      const bf16x8 va = *(const bf16x8*)(ui + q8*8);
      const bf16x8 vb = *(const bf16x8*)(uj + q8*8);
      #pragma unroll
      for (int j = 0; j < 8; ++j) {
        const int c = q8*8 + j;
        float v = bf2f((ushort_t)va[j]) + bf2f((ushort_t)vb[j]) + part[c];
        v = fmaxf(v, 0.f);
        ssum = fmaf(v, part[128 + c], ssum);
      }
    }
    out[(size_t)gid*OUT_PG + 1 + NPG*NOUT + tid] = ssum + e_b2[0];
  }
}

// ---------------------------------------------------------------------------
extern "C" void kernel_launch(void* const* d_in, const int* in_sizes, int n_in,
                              void* d_out, int out_size, void* d_ws, size_t ws_size,
                              hipStream_t stream) {
  const float* node_tab = (const float*)d_in[0];
  const float* edge_tab = (const float*)d_in[1];
  const float* c1_w  = (const float*)d_in[2];
  const float* c1_we = (const float*)d_in[3];
  const float* c1_as = (const float*)d_in[4];
  const float* c1_ad = (const float*)d_in[5];
  const float* c1_ae = (const float*)d_in[6];
  const float* c1_b  = (const float*)d_in[7];
  const float* c2_w  = (const float*)d_in[8];
  const float* c2_we = (const float*)d_in[9];
  const float* c2_as = (const float*)d_in[10];
  const float* c2_ad = (const float*)d_in[11];
  const float* c2_ae = (const float*)d_in[12];
  const float* c2_b  = (const float*)d_in[13];
  const float* s_w1  = (const float*)d_in[14];
  const float* s_b1  = (const float*)d_in[15];
  const float* s_w2  = (const float*)d_in[16];
  const float* s_b2  = (const float*)d_in[17];
  const float* n_w1  = (const float*)d_in[18];
  const float* n_b1  = (const float*)d_in[19];
  const float* n_w2  = (const float*)d_in[20];
  const float* n_b2  = (const float*)d_in[21];
  const float* e_w1  = (const float*)d_in[22];
  const float* e_b1  = (const float*)d_in[23];
  const float* e_w2  = (const float*)d_in[24];
  const float* e_b2  = (const float*)d_in[25];
  const int* x    = (const int*)d_in[26];
  const int* ei   = (const int*)d_in[27];
  const int* ea   = (const int*)d_in[28];
  const int* nedg = (const int*)d_in[29];
  float* out = (float*)d_out;

  prep_kernel<<<dim3(7), dim3(256), 0, stream>>>(
      edge_tab, c1_w, c1_we, c1_ae, c2_w, c2_we, c2_ae,
      s_w1, n_w1, n_w2, e_w1);

  graph_kernel<<<dim3(B_GR), dim3(256), 0, stream>>>(
      node_tab, c1_as, c1_ad, c1_b, c2_as, c2_ad, c2_b,
      s_b1, s_w2, s_b2, n_b1, n_b2, e_b1, e_w2, e_b2,
      x, ei, ea, nedg, out);
}

// Round 8
// 190.526 us; speedup vs baseline: 3.6113x; 1.0582x over previous
//
#include <hip/hip_runtime.h>

// ---------------------------------------------------------------------------
// GNN action-value net, MI355X. Round 8:
//  * prep widened 7 -> 44 blocks (2048-elem chunks; was 64 iters/thread,
//    ~35-55us of bench-vs-kernel gap in r4..r7).
//  * graph_kernel: P13+P15 fused (dual MFMA acc chains; u -> dead Hr region),
//    stop-head final stage folded into wave-0 regs (one fewer barrier),
//    nedg pairs + e_b1/e_w2 hoisted to P0. 10 barriers.
// LDS 38.9KB -> 4 blocks/CU (grid == exactly 4 blocks/CU).
// Fragment maps (verified r5-r7): A[m][k]: m=lane&15, k=(lane>>4)*8+j;
// B[k][n]: n=lane&15, k=(lane>>4)*8+j; C/D: col=lane&15, row=(lane>>4)*4+reg.
// ---------------------------------------------------------------------------

#define NPG 64
#define EPG 1024
#define NEPG 256
#define B_GR 1024
#define E_TOT 1048576
#define EMB 64
#define HID 128
#define NOUT 101
#define OUT_PG 6721            // 1 + 64*101 + 256

typedef __attribute__((ext_vector_type(8))) short bf16x8;
typedef __attribute__((ext_vector_type(4))) float f32x4;
typedef unsigned short ushort_t;

__device__ ushort_t g_c1w[EMB*HID];      // frag-packed bf16 (K=64)
__device__ ushort_t g_c2w[HID*HID];      // frag-packed bf16
__device__ ushort_t g_nw1[HID*HID];
__device__ ushort_t g_ew1[HID*HID];
__device__ ushort_t g_nw2[HID*112];      // N padded 101 -> 112
__device__ float    g_sw1t[HID*HID];     // s_w1 transposed, f32
__device__ float    g_he1[4], g_he2[4];

__device__ __forceinline__ ushort_t f2bf(float f) {
  unsigned u = __float_as_uint(f);
  return (ushort_t)((u + 0x7fffu + ((u >> 16) & 1u)) >> 16);
}
__device__ __forceinline__ float bf2f(ushort_t h) {
  return __uint_as_float(((unsigned)h) << 16);
}

// ---------------------------------------------------------------------------
// prep: 44 blocks. b0: logit-constant dots. b1-4: c1w. b5-12: c2w.
// b13-20: nw1. b21-28: ew1. b29-35: nw2. b36-43: sw1t.
__global__ void prep_kernel(
    const float* __restrict__ edge_tab,
    const float* __restrict__ c1_w,  const float* __restrict__ c1_we,
    const float* __restrict__ c1_ae,
    const float* __restrict__ c2_w,  const float* __restrict__ c2_we,
    const float* __restrict__ c2_ae,
    const float* __restrict__ s_w1,  const float* __restrict__ n_w1,
    const float* __restrict__ n_w2,  const float* __restrict__ e_w1)
{
  const int b = blockIdx.x, tid = threadIdx.x;
  if (b == 0) {                       // per-edge-type logit constants
    __shared__ float v1[EMB], v2[EMB];
    if (tid < EMB) {
      float a = 0.f, d = 0.f;
      for (int j = 0; j < HID; ++j) {
        a = fmaf(c1_we[tid*HID + j], c1_ae[j], a);
        d = fmaf(c2_we[tid*HID + j], c2_ae[j], d);
      }
      v1[tid] = a; v2[tid] = d;
    }
    __syncthreads();
    if (tid < 4) {
      float a = 0.f, d = 0.f;
      for (int k = 0; k < EMB; ++k) {
        const float ev = edge_tab[tid*EMB + k];
        a = fmaf(ev, v1[k], a); d = fmaf(ev, v2[k], d);
      }
      g_he1[tid] = a; g_he2[tid] = d;
    }
    return;
  }
  if (b <= 4) {                       // c1w: 8192 elems, 4 chunks
    const int base = (b - 1) * 2048 + tid;
    #pragma unroll
    for (int it = 0; it < 8; ++it) {
      const int idx = base + it*256;
      const int j = idx & 7, l = (idx >> 3) & 63, r2 = idx >> 9;
      const int ks = r2 & 1, ct = r2 >> 1;
      const int row = ks*32 + (l >> 4)*8 + j;
      const int col = ct*16 + (l & 15);
      g_c1w[idx] = f2bf(c1_w[row*HID + col]);
    }
    return;
  }
  if (b <= 28) {                      // c2w / nw1 / ew1: 16384 each, 8 chunks
    const int grp = (b - 5) >> 3;     // 0,1,2
    const int chunk = (b - 5) & 7;
    const float* W = (grp == 0) ? c2_w : (grp == 1) ? n_w1 : e_w1;
    ushort_t* G = (grp == 0) ? g_c2w : (grp == 1) ? g_nw1 : g_ew1;
    const int base = chunk * 2048 + tid;
    #pragma unroll
    for (int it = 0; it < 8; ++it) {
      const int idx = base + it*256;
      const int j = idx & 7, l = (idx >> 3) & 63, r2 = idx >> 9;
      const int ks = r2 & 3, ct = r2 >> 2;
      const int row = ks*32 + (l >> 4)*8 + j;
      const int col = ct*16 + (l & 15);
      G[idx] = f2bf(W[row*HID + col]);
    }
    return;
  }
  if (b <= 35) {                      // nw2: 14336, 7 chunks
    const int base = (b - 29) * 2048 + tid;
    #pragma unroll
    for (int it = 0; it < 8; ++it) {
      const int idx = base + it*256;
      const int j = idx & 7, l = (idx >> 3) & 63, r2 = idx >> 9;
      const int ks = r2 & 3, ct = r2 >> 2;     // ct 0..6
      const int row = ks*32 + (l >> 4)*8 + j;
      const int col = ct*16 + (l & 15);
      g_nw2[idx] = (col < NOUT) ? f2bf(n_w2[row*NOUT + col]) : (ushort_t)0;
    }
    return;
  }
  {                                   // sw1t: 16384, 8 chunks
    const int base = (b - 36) * 2048 + tid;
    #pragma unroll
    for (int it = 0; it < 8; ++it) {
      const int idx = base + it*256;
      g_sw1t[idx] = s_w1[(idx & 127)*HID + (idx >> 7)];
    }
  }
}

// ---------------------------------------------------------------------------
// LDS map (bytes). Region R overlays Pf(64x64 f32) / Hr(64x136 ushort).
#define S_HC   0        // 128x72 ushort col-major; reused as a1b 64x136 rows
#define S_R    18432    // max(Pf 16384, Hr 17408)
#define S_PART 35840    // 256 f32 (stop partials)
#define S_NS   36864    // 64 f32
#define S_ND   37120    // 64 f32
#define S_GP   37376    // 128 f32 (pool)
#define S_EBW  37888    // 256 f32: e_b1[0..127] | e_w2[0..127]
#define S_HCC  38912    // 8 f32
#define S_TOT  38944

__global__ __launch_bounds__(256, 4) void graph_kernel(
    const float* __restrict__ node_tab,
    const float* __restrict__ c1_as, const float* __restrict__ c1_ad,
    const float* __restrict__ c1_b,
    const float* __restrict__ c2_as, const float* __restrict__ c2_ad,
    const float* __restrict__ c2_b,
    const float* __restrict__ s_b1,  const float* __restrict__ s_w2,
    const float* __restrict__ s_b2,
    const float* __restrict__ n_b1,  const float* __restrict__ n_b2,
    const float* __restrict__ e_b1,  const float* __restrict__ e_w2,
    const float* __restrict__ e_b2,
    const int* __restrict__ x,  const int* __restrict__ ei,
    const int* __restrict__ ea, const int* __restrict__ nedg,
    float* __restrict__ out)
{
  const int tid = threadIdx.x;
  const int gid = blockIdx.x;
  const int nb = gid * NPG;
  const int lane = tid & 63;
  const int wv = tid >> 6;
  const int qd = lane >> 4;        // quad
  const int cl = lane & 15;        // col/row-in-tile
  const int rb = wv * 16;          // wave's M-tile base row

  __shared__ __align__(16) char smem[S_TOT];
  ushort_t* Hc   = (ushort_t*)(smem + S_HC);   // stride 72 (feat-major)
  float*    Pf   = (float*)   (smem + S_R);    // 64x64 f32
  ushort_t* Hr   = (ushort_t*)(smem + S_R);    // stride 136 (row-major)
  float*    part = (float*)   (smem + S_PART);
  float*    ns   = (float*)   (smem + S_NS);
  float*    nd   = (float*)   (smem + S_ND);
  float*    gp   = (float*)   (smem + S_GP);
  float*    ebw  = (float*)   (smem + S_EBW);
  float*    hc   = (float*)   (smem + S_HCC);
  ushort_t* a1b  = Hc;                         // 64x136 rows

  // ---- P0: edge regs, pair regs, emb frags, zero Pf/gp, consts ----
  unsigned er[4];
  #pragma unroll
  for (int i = 0; i < 4; ++i) {
    const int k = tid + 256*i;
    const int s = ei[gid*EPG + k] - nb;
    const int d = ei[E_TOT + gid*EPG + k] - nb;
    const int t = ea[gid*EPG + k];
    er[i] = (unsigned)(s | (d << 6) | (t << 12));
  }
  const int2 prr = *(const int2*)(nedg + 2*(gid*NEPG + tid));
  bf16x8 ea0, ea1;                 // emb A-frags for row rb+cl
  {
    const int cat = x[nb + rb + cl];
    const float* src = node_tab + cat*EMB;
    const float4 v0 = *(const float4*)(src + qd*8);
    const float4 v1 = *(const float4*)(src + qd*8 + 4);
    const float4 v2 = *(const float4*)(src + 32 + qd*8);
    const float4 v3 = *(const float4*)(src + 36 + qd*8);
    ea0[0]=f2bf(v0.x); ea0[1]=f2bf(v0.y); ea0[2]=f2bf(v0.z); ea0[3]=f2bf(v0.w);
    ea0[4]=f2bf(v1.x); ea0[5]=f2bf(v1.y); ea0[6]=f2bf(v1.z); ea0[7]=f2bf(v1.w);
    ea1[0]=f2bf(v2.x); ea1[1]=f2bf(v2.y); ea1[2]=f2bf(v2.z); ea1[3]=f2bf(v2.w);
    ea1[4]=f2bf(v3.x); ea1[5]=f2bf(v3.y); ea1[6]=f2bf(v3.z); ea1[7]=f2bf(v3.w);
  }
  {
    float4* pz = (float4*)Pf;
    #pragma unroll
    for (int j = 0; j < 4; ++j) pz[tid + j*256] = make_float4(0.f,0.f,0.f,0.f);
  }
  if (tid < 128) gp[tid] = 0.f;
  ebw[tid] = (tid < 128) ? e_b1[tid] : e_w2[tid - 128];
  if (tid < 8) hc[tid] = (tid < 4) ? g_he1[tid] : g_he2[tid-4];

  // ---- P2: h1pre = emb @ c1_w (MFMA) -> Hc col-major + ns/nd ----
  {
    float pns[4] = {0.f,0.f,0.f,0.f}, pnd[4] = {0.f,0.f,0.f,0.f};
    #pragma unroll
    for (int ct = 0; ct < 8; ++ct) {
      f32x4 acc = {0.f, 0.f, 0.f, 0.f};
      const bf16x8 b0 = *(const bf16x8*)(g_c1w + ((ct*2+0)*64 + lane)*8);
      const bf16x8 b1 = *(const bf16x8*)(g_c1w + ((ct*2+1)*64 + lane)*8);
      acc = __builtin_amdgcn_mfma_f32_16x16x32_bf16(ea0, b0, acc, 0, 0, 0);
      acc = __builtin_amdgcn_mfma_f32_16x16x32_bf16(ea1, b1, acc, 0, 0, 0);
      const int n = ct*16 + cl;
      const float asv = c1_as[n], adv = c1_ad[n];
      #pragma unroll
      for (int r = 0; r < 4; ++r) {
        const float v = acc[r];
        Hc[n*72 + (rb + qd*4 + r)] = f2bf(v);
        pns[r] = fmaf(v, asv, pns[r]);
        pnd[r] = fmaf(v, adv, pnd[r]);
      }
    }
    #pragma unroll
    for (int r = 0; r < 4; ++r) {
      #pragma unroll
      for (int off = 1; off < 16; off <<= 1) {
        pns[r] += __shfl_xor(pns[r], off, 64);
        pnd[r] += __shfl_xor(pnd[r], off, 64);
      }
    }
    if (cl == 0) {
      #pragma unroll
      for (int r = 0; r < 4; ++r) { ns[rb+qd*4+r] = pns[r]; nd[rb+qd*4+r] = pnd[r]; }
    }
  }
  __syncthreads();                                        // B2

  // ---- edge pass 1 ----
  #pragma unroll
  for (int i = 0; i < 4; ++i) {
    const unsigned tp = er[i];
    const int s = tp & 63, d = (tp >> 6) & 63, t = tp >> 12;
    float l = ns[s] + nd[d] + hc[t];
    l = (l > 0.f) ? l : 0.2f * l;
    atomicAdd(&Pf[d*64 + s], __expf(l));
  }
  __syncthreads();                                        // B3

  // ---- agg1 preload: P frags (f32->bf16 in-reg) + den rowsum ----
  bf16x8 pa0, pa1;
  float inv4[4];
  {
    const float* pr = Pf + (rb + cl)*64;
    const float4 v0 = *(const float4*)(pr + qd*8);
    const float4 v1 = *(const float4*)(pr + qd*8 + 4);
    const float4 v2 = *(const float4*)(pr + 32 + qd*8);
    const float4 v3 = *(const float4*)(pr + 36 + qd*8);
    pa0[0]=f2bf(v0.x); pa0[1]=f2bf(v0.y); pa0[2]=f2bf(v0.z); pa0[3]=f2bf(v0.w);
    pa0[4]=f2bf(v1.x); pa0[5]=f2bf(v1.y); pa0[6]=f2bf(v1.z); pa0[7]=f2bf(v1.w);
    pa1[0]=f2bf(v2.x); pa1[1]=f2bf(v2.y); pa1[2]=f2bf(v2.z); pa1[3]=f2bf(v2.w);
    pa1[4]=f2bf(v3.x); pa1[5]=f2bf(v3.y); pa1[6]=f2bf(v3.z); pa1[7]=f2bf(v3.w);
    float den = v0.x+v0.y+v0.z+v0.w + v1.x+v1.y+v1.z+v1.w
              + v2.x+v2.y+v2.z+v2.w + v3.x+v3.y+v3.z+v3.w;
    den += __shfl_xor(den, 16, 64);
    den += __shfl_xor(den, 32, 64);
    #pragma unroll
    for (int r = 0; r < 4; ++r)
      inv4[r] = 1.f / (__shfl(den, qd*4 + r, 64) + 1e-16f);
  }
  __syncthreads();                                        // B4

  // ---- agg1: h1 = relu(inv*(P@h1pre) + c1_b) -> Hr ----
  {
    #pragma unroll
    for (int ct = 0; ct < 8; ++ct) {
      f32x4 acc = {0.f, 0.f, 0.f, 0.f};
      const bf16x8 b0 = *(const bf16x8*)(Hc + (ct*16+cl)*72 + qd*8);
      const bf16x8 b1 = *(const bf16x8*)(Hc + (ct*16+cl)*72 + 32 + qd*8);
      acc = __builtin_amdgcn_mfma_f32_16x16x32_bf16(pa0, b0, acc, 0, 0, 0);
      acc = __builtin_amdgcn_mfma_f32_16x16x32_bf16(pa1, b1, acc, 0, 0, 0);
      const int n = ct*16 + cl;
      const float bias = c1_b[n];
      #pragma unroll
      for (int r = 0; r < 4; ++r)
        Hr[(rb + qd*4 + r)*136 + n] = f2bf(fmaxf(fmaf(acc[r], inv4[r], bias), 0.f));
    }
  }
  bf16x8 h1f[4];                     // wave-local rows, no barrier needed
  #pragma unroll
  for (int ks = 0; ks < 4; ++ks)
    h1f[ks] = *(const bf16x8*)(Hr + (rb+cl)*136 + ks*32 + qd*8);
  __syncthreads();                                        // B5

  // ---- P7: h2pre = h1 @ c2_w -> Hc + ns/nd; zero Pf ----
  {
    float4* pz = (float4*)Pf;
    #pragma unroll
    for (int j = 0; j < 4; ++j) pz[tid + j*256] = make_float4(0.f,0.f,0.f,0.f);
    float pns[4] = {0.f,0.f,0.f,0.f}, pnd[4] = {0.f,0.f,0.f,0.f};
    #pragma unroll
    for (int ct = 0; ct < 8; ++ct) {
      f32x4 acc = {0.f, 0.f, 0.f, 0.f};
      #pragma unroll
      for (int ks = 0; ks < 4; ++ks) {
        const bf16x8 b = *(const bf16x8*)(g_c2w + ((ct*4+ks)*64 + lane)*8);
        acc = __builtin_amdgcn_mfma_f32_16x16x32_bf16(h1f[ks], b, acc, 0, 0, 0);
      }
      const int n = ct*16 + cl;
      const float asv = c2_as[n], adv = c2_ad[n];
      #pragma unroll
      for (int r = 0; r < 4; ++r) {
        const float v = acc[r];
        Hc[n*72 + (rb + qd*4 + r)] = f2bf(v);
        pns[r] = fmaf(v, asv, pns[r]);
        pnd[r] = fmaf(v, adv, pnd[r]);
      }
    }
    #pragma unroll
    for (int r = 0; r < 4; ++r) {
      #pragma unroll
      for (int off = 1; off < 16; off <<= 1) {
        pns[r] += __shfl_xor(pns[r], off, 64);
        pnd[r] += __shfl_xor(pnd[r], off, 64);
      }
    }
    if (cl == 0) {
      #pragma unroll
      for (int r = 0; r < 4; ++r) { ns[rb+qd*4+r] = pns[r]; nd[rb+qd*4+r] = pnd[r]; }
    }
  }
  __syncthreads();                                        // B6

  // ---- edge pass 2 ----
  #pragma unroll
  for (int i = 0; i < 4; ++i) {
    const unsigned tp = er[i];
    const int s = tp & 63, d = (tp >> 6) & 63, t = tp >> 12;
    float l = ns[s] + nd[d] + hc[4 + t];
    l = (l > 0.f) ? l : 0.2f * l;
    atomicAdd(&Pf[d*64 + s], __expf(l));
  }
  __syncthreads();                                        // B7

  // ---- agg2 preload ----
  {
    const float* pr = Pf + (rb + cl)*64;
    const float4 v0 = *(const float4*)(pr + qd*8);
    const float4 v1 = *(const float4*)(pr + qd*8 + 4);
    const float4 v2 = *(const float4*)(pr + 32 + qd*8);
    const float4 v3 = *(const float4*)(pr + 36 + qd*8);
    pa0[0]=f2bf(v0.x); pa0[1]=f2bf(v0.y); pa0[2]=f2bf(v0.z); pa0[3]=f2bf(v0.w);
    pa0[4]=f2bf(v1.x); pa0[5]=f2bf(v1.y); pa0[6]=f2bf(v1.z); pa0[7]=f2bf(v1.w);
    pa1[0]=f2bf(v2.x); pa1[1]=f2bf(v2.y); pa1[2]=f2bf(v2.z); pa1[3]=f2bf(v2.w);
    pa1[4]=f2bf(v3.x); pa1[5]=f2bf(v3.y); pa1[6]=f2bf(v3.z); pa1[7]=f2bf(v3.w);
    float den = v0.x+v0.y+v0.z+v0.w + v1.x+v1.y+v1.z+v1.w
              + v2.x+v2.y+v2.z+v2.w + v3.x+v3.y+v3.z+v3.w;
    den += __shfl_xor(den, 16, 64);
    den += __shfl_xor(den, 32, 64);
    #pragma unroll
    for (int r = 0; r < 4; ++r)
      inv4[r] = 1.f / (__shfl(den, qd*4 + r, 64) + 1e-16f);
  }
  __syncthreads();                                        // B8

  // ---- agg2: h2 = inv*(P@h2pre) + c2_b -> Hr + pooling ----
  {
    #pragma unroll
    for (int ct = 0; ct < 8; ++ct) {
      f32x4 acc = {0.f, 0.f, 0.f, 0.f};
      const bf16x8 b0 = *(const bf16x8*)(Hc + (ct*16+cl)*72 + qd*8);
      const bf16x8 b1 = *(const bf16x8*)(Hc + (ct*16+cl)*72 + 32 + qd*8);
      acc = __builtin_amdgcn_mfma_f32_16x16x32_bf16(pa0, b0, acc, 0, 0, 0);
      acc = __builtin_amdgcn_mfma_f32_16x16x32_bf16(pa1, b1, acc, 0, 0, 0);
      const int n = ct*16 + cl;
      const float bias = c2_b[n];
      float colsum = 0.f;
      #pragma unroll
      for (int r = 0; r < 4; ++r) {
        const float v = fmaf(acc[r], inv4[r], bias);
        Hr[(rb + qd*4 + r)*136 + n] = f2bf(v);
        colsum += v;
      }
      colsum += __shfl_xor(colsum, 16, 64);
      colsum += __shfl_xor(colsum, 32, 64);
      if (qd == 0) atomicAdd(&gp[n], colsum);
    }
  }
  __syncthreads();                                        // B9

  // ---- stop head partials ----
  {
    const int j = tid & 127, half = tid >> 7;
    const float* wr = g_sw1t + j*HID + half*64;
    const float* gr = gp + half*64;
    float p = 0.f;
    #pragma unroll
    for (int q = 0; q < 16; ++q) {
      const float4 w = ((const float4*)wr)[q];
      const float4 g = ((const float4*)gr)[q];
      p = fmaf(w.x, g.x, p); p = fmaf(w.y, g.y, p);
      p = fmaf(w.z, g.z, p); p = fmaf(w.w, g.w, p);
    }
    part[tid] = p;
  }
  __syncthreads();                                        // B10

  // ---- post-B10: stop reduce (wave 0), fused addnode/addedge staging ----
  if (tid < 64) {
    const float z0 = fmaxf(part[tid] + part[tid+128] + s_b1[tid], 0.f);
    const float z1 = fmaxf(part[tid+64] + part[tid+192] + s_b1[tid+64], 0.f);
    float p = fmaf(z0, s_w2[tid], z1 * s_w2[tid+64]);
    #pragma unroll
    for (int off = 32; off > 0; off >>= 1) p += __shfl_down(p, off, 64);
    if (tid == 0) out[(size_t)gid*OUT_PG] = p + s_b2[0];
  }

  bf16x8 h2f[4];                    // own-wave h2 rows (agg2 wrote them)
  #pragma unroll
  for (int ks = 0; ks < 4; ++ks)
    h2f[ks] = *(const bf16x8*)(Hr + (rb+cl)*136 + ks*32 + qd*8);

  // fused: a1 = relu(h2@n_w1+n_b1) -> a1b(Hc);  u = h2@e_w1 -> Hr (own rows)
  {
    #pragma unroll
    for (int ct = 0; ct < 8; ++ct) {
      f32x4 an = {0.f, 0.f, 0.f, 0.f};
      f32x4 ae2 = {0.f, 0.f, 0.f, 0.f};
      #pragma unroll
      for (int ks = 0; ks < 4; ++ks) {
        const bf16x8 bn = *(const bf16x8*)(g_nw1 + ((ct*4+ks)*64 + lane)*8);
        const bf16x8 be = *(const bf16x8*)(g_ew1 + ((ct*4+ks)*64 + lane)*8);
        an  = __builtin_amdgcn_mfma_f32_16x16x32_bf16(h2f[ks], bn, an, 0, 0, 0);
        ae2 = __builtin_amdgcn_mfma_f32_16x16x32_bf16(h2f[ks], be, ae2, 0, 0, 0);
      }
      const int n = ct*16 + cl;
      const float bias = n_b1[n];
      #pragma unroll
      for (int r = 0; r < 4; ++r) {
        a1b[(rb + qd*4 + r)*136 + n] = f2bf(fmaxf(an[r] + bias, 0.f));
        Hr[(rb + qd*4 + r)*136 + n] = f2bf(ae2[r]);
      }
    }
  }
  // addnode head: out = a1 @ n_w2p + n_b2 (own-wave a1b rows)
  {
    bf16x8 af[4];
    #pragma unroll
    for (int ks = 0; ks < 4; ++ks)
      af[ks] = *(const bf16x8*)(a1b + (rb+cl)*136 + ks*32 + qd*8);
    float* ob = out + (size_t)gid*OUT_PG + 1;
    #pragma unroll
    for (int ct = 0; ct < 7; ++ct) {
      f32x4 acc = {0.f, 0.f, 0.f, 0.f};
      #pragma unroll
      for (int ks = 0; ks < 4; ++ks) {
        const bf16x8 b = *(const bf16x8*)(g_nw2 + ((ct*4+ks)*64 + lane)*8);
        acc = __builtin_amdgcn_mfma_f32_16x16x32_bf16(af[ks], b, acc, 0, 0, 0);
      }
      const int o = ct*16 + cl;
      if (o < NOUT) {
        const float b2 = n_b2[o];
        #pragma unroll
        for (int r = 0; r < 4; ++r)
          ob[(size_t)(rb + qd*4 + r)*NOUT + o] = acc[r] + b2;
      }
    }
  }
  __syncthreads();                                        // B12

  // ---- addedge pairs (u in Hr region) ----
  {
    const ushort_t* ui = Hr + (prr.x - nb)*136;
    const ushort_t* uj = Hr + (prr.y - nb)*136;
    float ssum = 0.f;
    #pragma unroll
    for (int q8 = 0; q8 < 16; ++q8) {
      const bf16x8 va = *(const bf16x8*)(ui + q8*8);
      const bf16x8 vb = *(const bf16x8*)(uj + q8*8);
      #pragma unroll
      for (int j = 0; j < 8; ++j) {
        const int c = q8*8 + j;
        float v = bf2f((ushort_t)va[j]) + bf2f((ushort_t)vb[j]) + ebw[c];
        v = fmaxf(v, 0.f);
        ssum = fmaf(v, ebw[128 + c], ssum);
      }
    }
    out[(size_t)gid*OUT_PG + 1 + NPG*NOUT + tid] = ssum + e_b2[0];
  }
}

// ---------------------------------------------------------------------------
extern "C" void kernel_launch(void* const* d_in, const int* in_sizes, int n_in,
                              void* d_out, int out_size, void* d_ws, size_t ws_size,
                              hipStream_t stream) {
  const float* node_tab = (const float*)d_in[0];
  const float* edge_tab = (const float*)d_in[1];
  const float* c1_w  = (const float*)d_in[2];
  const float* c1_we = (const float*)d_in[3];
  const float* c1_as = (const float*)d_in[4];
  const float* c1_ad = (const float*)d_in[5];
  const float* c1_ae = (const float*)d_in[6];
  const float* c1_b  = (const float*)d_in[7];
  const float* c2_w  = (const float*)d_in[8];
  const float* c2_we = (const float*)d_in[9];
  const float* c2_as = (const float*)d_in[10];
  const float* c2_ad = (const float*)d_in[11];
  const float* c2_ae = (const float*)d_in[12];
  const float* c2_b  = (const float*)d_in[13];
  const float* s_w1  = (const float*)d_in[14];
  const float* s_b1  = (const float*)d_in[15];
  const float* s_w2  = (const float*)d_in[16];
  const float* s_b2  = (const float*)d_in[17];
  const float* n_w1  = (const float*)d_in[18];
  const float* n_b1  = (const float*)d_in[19];
  const float* n_w2  = (const float*)d_in[20];
  const float* n_b2  = (const float*)d_in[21];
  const float* e_w1  = (const float*)d_in[22];
  const float* e_b1  = (const float*)d_in[23];
  const float* e_w2  = (const float*)d_in[24];
  const float* e_b2  = (const float*)d_in[25];
  const int* x    = (const int*)d_in[26];
  const int* ei   = (const int*)d_in[27];
  const int* ea   = (const int*)d_in[28];
  const int* nedg = (const int*)d_in[29];
  float* out = (float*)d_out;

  prep_kernel<<<dim3(44), dim3(256), 0, stream>>>(
      edge_tab, c1_w, c1_we, c1_ae, c2_w, c2_we, c2_ae,
      s_w1, n_w1, n_w2, e_w1);

  graph_kernel<<<dim3(B_GR), dim3(256), 0, stream>>>(
      node_tab, c1_as, c1_ad, c1_b, c2_as, c2_ad, c2_b,
      s_b1, s_w2, s_b2, n_b1, n_b2, e_b1, e_w2, e_b2,
      x, ei, ea, nedg, out);
}